// Round 2
// baseline (2492.012 us; speedup 1.0000x reference)
//
#include <hip/hip_runtime.h>
#include <math.h>
#include <stddef.h>

#define N0   4096
#define NE   131072
#define FIN  1433
#define HID  32
#define NCLS 16
#define KP1  2000
#define KP2  1000
#define KP3  500

// ---------------- basic utils ----------------

__global__ __launch_bounds__(256) void k_fill0_u32(unsigned* p, size_t n) {
    size_t i = (size_t)blockIdx.x * blockDim.x + threadIdx.x;
    size_t st = (size_t)gridDim.x * blockDim.x;
    for (; i < n; i += st) p[i] = 0u;
}

__global__ __launch_bounds__(256) void k_copy(float* dst, const float* src, int n) {
    int i = blockIdx.x * blockDim.x + threadIdx.x;
    if (i < n) dst[i] = src[i];
}

// scatter edges into packed-u8 dense adjacency via byte-lane atomicAdd on u32 (exact small counts)
__global__ __launch_bounds__(256) void k_scatter(const int* ei, unsigned* A0w) {
    int e = blockIdx.x * blockDim.x + threadIdx.x;
    if (e >= NE) return;
    int r = ei[e], c = ei[NE + e];
    if (r == c) return;
    size_t idx = (size_t)r * N0 + c;
    atomicAdd(&A0w[idx >> 2], 1u << (8 * (idx & 3)));
}

// deg[i] = rowsum(A) + 2 (improved self loop), dv[i] = 1/sqrt(deg)
template <class T>
__global__ __launch_bounds__(256) void k_deg(const T* A, int n, float* dv) {
    int i = blockIdx.x;
    const T* row = A + (size_t)i * n;
    float acc = 0.f;
    for (int j = threadIdx.x; j < n; j += 256) acc += (float)row[j];
    __shared__ float red[256];
    red[threadIdx.x] = acc; __syncthreads();
    for (int off = 128; off > 0; off >>= 1) {
        if (threadIdx.x < off) red[threadIdx.x] += red[threadIdx.x + off];
        __syncthreads();
    }
    if (threadIdx.x == 0) {
        double deg = (double)red[0] + 2.0;
        dv[i] = (float)(1.0 / sqrt(deg));
    }
}

// XW[i][c] = sum_k X[i][k] * W[k][c].  One block per row, split-K across thread groups.
__global__ __launch_bounds__(256) void k_xw(const float* X, const float* W, float* XW, int K, int NC) {
    int i = blockIdx.x;
    int c = threadIdx.x % NC, g = threadIdx.x / NC;
    int G = 256 / NC;
    const float* xr = X + (size_t)i * K;
    float acc = 0.f;
    for (int k = g; k < K; k += G) acc += xr[k] * W[(size_t)k * NC + c];
    __shared__ float red[256];
    red[threadIdx.x] = acc; __syncthreads();
    for (int off = 128; off >= NC; off >>= 1) {
        if (threadIdx.x < off) red[threadIdx.x] += red[threadIdx.x + off];
        __syncthreads();
    }
    if (threadIdx.x < NC) XW[(size_t)i * NC + threadIdx.x] = red[threadIdx.x];
}

__global__ __launch_bounds__(256) void k_scaley(const float* xw, const float* dv, float* y, int tot, int NC) {
    int i = blockIdx.x * blockDim.x + threadIdx.x;
    if (i < tot) y[i] = dv[i / NC] * xw[i];
}

// out[i][c] = dv[i]*sum_j A[i][j]*y[j][c] + 2*dv[i]*y[i][c] + b[c]  (y = dv .* xw), optional relu
template <class T>
__global__ __launch_bounds__(256) void k_spmm(const T* A, const float* y, const float* dv,
                                              const float* bias, float* out, int n, int NC, int relu) {
    int i = blockIdx.x;
    int c = threadIdx.x % NC, g = threadIdx.x / NC;
    int G = 256 / NC;
    const T* row = A + (size_t)i * n;
    float acc = 0.f;
    for (int j = g; j < n; j += G) acc += (float)row[j] * y[(size_t)j * NC + c];
    __shared__ float red[256];
    red[threadIdx.x] = acc; __syncthreads();
    for (int off = 128; off >= NC; off >>= 1) {
        if (threadIdx.x < off) red[threadIdx.x] += red[threadIdx.x + off];
        __syncthreads();
    }
    if (threadIdx.x < NC) {
        float di = dv[i];
        float v = di * red[threadIdx.x] + 2.f * di * y[(size_t)i * NC + threadIdx.x] + bias[threadIdx.x];
        if (relu) v = fmaxf(v, 0.f);
        out[(size_t)i * NC + threadIdx.x] = v;
    }
}

// ---------------- top-k pooling ----------------

__global__ __launch_bounds__(256) void k_score(const float* x, const float* p, float* s, int n) {
    int i = blockIdx.x * blockDim.x + threadIdx.x;
    if (i >= n) return;
    float nrm = 0.f;
    for (int c = 0; c < HID; c++) nrm += p[c] * p[c];
    nrm = sqrtf(nrm);
    const float* xr = x + (size_t)i * HID;
    float d = 0.f;
    for (int c = 0; c < HID; c++) d += xr[c] * p[c];
    s[i] = tanhf(d / nrm);
}

// rank[i] = #{j : s[j] > s[i]  or (s[j]==s[i] and j<i)}  -> exact lax.top_k order
__global__ __launch_bounds__(256) void k_rank(const float* s, int* rk, int n) {
    int i = blockIdx.x * blockDim.x + threadIdx.x;
    if (i >= n) return;
    float si = s[i];
    int r = 0;
    for (int j = 0; j < n; j++) {
        float sj = s[j];
        r += (sj > si) || (sj == si && j < i);
    }
    rk[i] = r;
}

__global__ __launch_bounds__(256) void k_perm(const int* rk, int* perm, int n, int k) {
    int i = blockIdx.x * blockDim.x + threadIdx.x;
    if (i >= n) return;
    int r = rk[i];
    if (r < k) perm[r] = i;
}

__global__ __launch_bounds__(256) void k_poolx(const float* x, const float* s, const int* perm, float* xp, int k) {
    int idx = blockIdx.x * blockDim.x + threadIdx.x;
    if (idx >= k * HID) return;
    int r = idx / HID, c = idx % HID;
    int pr = perm[r];
    xp[idx] = x[(size_t)pr * HID + c] * s[pr];
}

// ---------------- fused augment + pool:  Ap = ((A+I)@(A+I))[perm][:,perm], zero diag ----------------

// pre-gather columns: CG[k][r2] = A[k][perm[r2]] + (k==perm[r2]); CG same elem type as A
template <class T>
__global__ __launch_bounds__(256) void k_gcols(const T* A, const int* perm, T* CG, int n, int kk) {
    size_t idx = (size_t)blockIdx.x * blockDim.x + threadIdx.x;
    if (idx >= (size_t)n * kk) return;
    int k = (int)(idx / kk), r2 = (int)(idx % kk);
    int pc = perm[r2];
    T v = A[(size_t)k * n + pc];
    if (k == pc) v = (T)(v + (T)1);
    CG[idx] = v;
}

// C[r1][r2] = sum_k (A[perm[r1]][k] + I) * CG[k][r2]; 64x64 tiles, 4x4 per thread; fp32 accum (exact ints)
template <class T>
__global__ __launch_bounds__(256) void k_gemm_pool(const T* A, const int* perm, const T* CG,
                                                   float* Ap, int n, int kk) {
    __shared__ float As[16][65];   // [k][row]
    __shared__ float Bs[16][65];   // [k][col]
    __shared__ int   pr[64];
    int r0 = blockIdx.y * 64, c0 = blockIdx.x * 64;
    int tx = threadIdx.x % 16, ty = threadIdx.x / 16;

    for (int t = threadIdx.x; t < 64; t += 256) {
        int rg = r0 + t;
        pr[t] = (rg < kk) ? perm[rg] : -1;
    }
    __syncthreads();

    float acc[4][4] = {};
    int cB = threadIdx.x % 64, kB = threadIdx.x / 64;

    for (int k0 = 0; k0 < n; k0 += 16) {
        for (int pass = 0; pass < 4; pass++) {
            int r = ty + pass * 16;
            int kk_ = k0 + tx;
            int prow = pr[r];
            float v = 0.f;
            if (prow >= 0 && kk_ < n) {
                v = (float)A[(size_t)prow * n + kk_];
                if (prow == kk_) v += 1.f;
            }
            As[tx][r] = v;
        }
        for (int pass = 0; pass < 4; pass++) {
            int k = kB + 4 * pass;
            int cg = c0 + cB;
            float v = 0.f;
            if (cg < kk && (k0 + k) < n) v = (float)CG[(size_t)(k0 + k) * kk + cg];
            Bs[k][cB] = v;
        }
        __syncthreads();
        for (int k = 0; k < 16; k++) {
            float a[4], b[4];
            #pragma unroll
            for (int i = 0; i < 4; i++) a[i] = As[k][ty * 4 + i];
            #pragma unroll
            for (int j = 0; j < 4; j++) b[j] = Bs[k][tx * 4 + j];
            #pragma unroll
            for (int i = 0; i < 4; i++)
                #pragma unroll
                for (int j = 0; j < 4; j++) acc[i][j] += a[i] * b[j];
        }
        __syncthreads();
    }
    for (int i = 0; i < 4; i++) {
        int rg = r0 + ty * 4 + i;
        if (rg >= kk) continue;
        for (int j = 0; j < 4; j++) {
            int cg = c0 + tx * 4 + j;
            if (cg >= kk) continue;
            Ap[(size_t)rg * kk + cg] = (rg == cg) ? 0.f : acc[i][j];
        }
    }
}

// ---------------- up path + output ----------------

__global__ __launch_bounds__(256) void k_scadd(float* h, const float* xs, const int* perm, int k) {
    int idx = blockIdx.x * blockDim.x + threadIdx.x;
    if (idx >= k * HID) return;
    int r = idx / HID, c = idx % HID;
    h[(size_t)perm[r] * HID + c] += xs[idx];
}

__global__ __launch_bounds__(256) void k_logsm(const float* in, float* out, int n) {
    int i = blockIdx.x * blockDim.x + threadIdx.x;
    if (i >= n) return;
    const float* r = in + (size_t)i * NCLS;
    float m = -1e30f;
    for (int c = 0; c < NCLS; c++) m = fmaxf(m, r[c]);
    float sum = 0.f;
    for (int c = 0; c < NCLS; c++) sum += expf(r[c] - m);
    float ls = logf(sum);
    float* o = out + (size_t)i * NCLS;
    for (int c = 0; c < NCLS; c++) o[c] = r[c] - m - ls;
}

// ---------------- host ----------------

extern "C" void kernel_launch(void* const* d_in, const int* in_sizes, int n_in,
                              void* d_out, int out_size, void* d_ws, size_t ws_size,
                              hipStream_t stream) {
    const float* x  = (const float*)d_in[0];
    const int*   ei = (const int*)d_in[1];   // harness passes integer inputs as int32
    const float* W0 = (const float*)d_in[2];  const float* b0 = (const float*)d_in[3];
    const float* W1 = (const float*)d_in[4];  const float* b1 = (const float*)d_in[5];
    const float* W2 = (const float*)d_in[6];  const float* b2 = (const float*)d_in[7];
    const float* W3 = (const float*)d_in[8];  const float* b3 = (const float*)d_in[9];
    const float* U0 = (const float*)d_in[10]; const float* c0 = (const float*)d_in[11];
    const float* U1 = (const float*)d_in[12]; const float* c1 = (const float*)d_in[13];
    const float* U2 = (const float*)d_in[14]; const float* c2 = (const float*)d_in[15];
    const float* p0 = (const float*)d_in[16];
    const float* p1 = (const float*)d_in[17];
    const float* p2 = (const float*)d_in[18];
    float* out = (float*)d_out;

    char* w = (char*)d_ws;
    size_t off = 0;
    auto alloc = [&](size_t bytes) -> void* {
        void* p = w + off;
        off += (bytes + 255) / 256 * 256;
        return p;
    };
    unsigned char* A0u = (unsigned char*)alloc((size_t)N0 * N0);          // 16.8 MB
    float* A1  = (float*)alloc((size_t)KP1 * KP1 * 4);                    // 16 MB
    float* A2  = (float*)alloc((size_t)KP2 * KP2 * 4);                    // 4 MB
    float* A3  = (float*)alloc((size_t)KP3 * KP3 * 4);                    // 1 MB
    void*  CG  = alloc((size_t)N0 * KP1);                                 // 8.2 MB (u8 L0 / f32 L1,L2)
    float* x0  = (float*)alloc((size_t)N0 * HID * 4);
    float* x1  = (float*)alloc((size_t)KP1 * HID * 4);
    float* x2  = (float*)alloc((size_t)KP2 * HID * 4);
    float* x3  = (float*)alloc((size_t)KP3 * HID * 4);
    float* xp  = (float*)alloc((size_t)KP1 * HID * 4);
    float* ua  = (float*)alloc((size_t)KP2 * HID * 4);
    float* ub  = (float*)alloc((size_t)KP1 * HID * 4);
    float* hb  = (float*)alloc((size_t)N0 * HID * 4);
    float* xw  = (float*)alloc((size_t)N0 * HID * 4);
    float* yb  = (float*)alloc((size_t)N0 * HID * 4);
    float* dv  = (float*)alloc((size_t)N0 * 4);
    float* sc  = (float*)alloc((size_t)N0 * 4);
    float* o16 = (float*)alloc((size_t)N0 * NCLS * 4);
    int*   rk  = (int*)alloc((size_t)N0 * 4);
    int*   pm0 = (int*)alloc((size_t)KP1 * 4);
    int*   pm1 = (int*)alloc((size_t)KP2 * 4);
    int*   pm2 = (int*)alloc((size_t)KP3 * 4);
    (void)ws_size; (void)in_sizes; (void)n_in; (void)out_size;

    auto gcn_u8 = [&](const unsigned char* A, int n, const float* xin, int K,
                      const float* W, const float* bias, int NC, int relu, float* outv) {
        k_deg<unsigned char><<<n, 256, 0, stream>>>(A, n, dv);
        k_xw<<<n, 256, 0, stream>>>(xin, W, xw, K, NC);
        int tot = n * NC;
        k_scaley<<<(tot + 255) / 256, 256, 0, stream>>>(xw, dv, yb, tot, NC);
        k_spmm<unsigned char><<<n, 256, 0, stream>>>(A, yb, dv, bias, outv, n, NC, relu);
    };
    auto gcn_f = [&](const float* A, int n, const float* xin, int K,
                     const float* W, const float* bias, int NC, int relu, float* outv) {
        k_deg<float><<<n, 256, 0, stream>>>(A, n, dv);
        k_xw<<<n, 256, 0, stream>>>(xin, W, xw, K, NC);
        int tot = n * NC;
        k_scaley<<<(tot + 255) / 256, 256, 0, stream>>>(xw, dv, yb, tot, NC);
        k_spmm<float><<<n, 256, 0, stream>>>(A, yb, dv, bias, outv, n, NC, relu);
    };
    auto pool = [&](const float* xin, const float* p, int n, int k, int* perm, float* xpo) {
        k_score<<<(n + 255) / 256, 256, 0, stream>>>(xin, p, sc, n);
        k_rank<<<(n + 255) / 256, 256, 0, stream>>>(sc, rk, n);
        k_perm<<<(n + 255) / 256, 256, 0, stream>>>(rk, perm, n, k);
        k_poolx<<<(k * HID + 255) / 256, 256, 0, stream>>>(xin, sc, perm, xpo, k);
    };
    auto augpool_u8 = [&](const unsigned char* A, int n, const int* perm, int kk, float* Ap) {
        size_t tot = (size_t)n * kk;
        unsigned char* cg = (unsigned char*)CG;
        k_gcols<unsigned char><<<(int)((tot + 255) / 256), 256, 0, stream>>>(A, perm, cg, n, kk);
        dim3 g((kk + 63) / 64, (kk + 63) / 64);
        k_gemm_pool<unsigned char><<<g, 256, 0, stream>>>(A, perm, cg, Ap, n, kk);
    };
    auto augpool_f = [&](const float* A, int n, const int* perm, int kk, float* Ap) {
        size_t tot = (size_t)n * kk;
        float* cg = (float*)CG;
        k_gcols<float><<<(int)((tot + 255) / 256), 256, 0, stream>>>(A, perm, cg, n, kk);
        dim3 g((kk + 63) / 64, (kk + 63) / 64);
        k_gemm_pool<float><<<g, 256, 0, stream>>>(A, perm, cg, Ap, n, kk);
    };

    // build dense adjacency (u8 packed)
    k_fill0_u32<<<2048, 256, 0, stream>>>((unsigned*)A0u, (size_t)N0 * N0 / 4);
    k_scatter<<<(NE + 255) / 256, 256, 0, stream>>>(ei, (unsigned*)A0u);

    // down path
    gcn_u8(A0u, N0, x, FIN, W0, b0, HID, 1, x0);
    pool(x0, p0, N0, KP1, pm0, xp);
    augpool_u8(A0u, N0, pm0, KP1, A1);
    gcn_f(A1, KP1, xp, HID, W1, b1, HID, 1, x1);
    pool(x1, p1, KP1, KP2, pm1, xp);
    augpool_f(A1, KP1, pm1, KP2, A2);
    gcn_f(A2, KP2, xp, HID, W2, b2, HID, 1, x2);
    pool(x2, p2, KP2, KP3, pm2, xp);
    augpool_f(A2, KP2, pm2, KP3, A3);
    gcn_f(A3, KP3, xp, HID, W3, b3, HID, 1, x3);

    // up path
    k_copy<<<(KP2 * HID + 255) / 256, 256, 0, stream>>>(hb, x2, KP2 * HID);
    k_scadd<<<(KP3 * HID + 255) / 256, 256, 0, stream>>>(hb, x3, pm2, KP3);
    gcn_f(A2, KP2, hb, HID, U0, c0, HID, 1, ua);

    k_copy<<<(KP1 * HID + 255) / 256, 256, 0, stream>>>(hb, x1, KP1 * HID);
    k_scadd<<<(KP2 * HID + 255) / 256, 256, 0, stream>>>(hb, ua, pm1, KP2);
    gcn_f(A1, KP1, hb, HID, U1, c1, HID, 1, ub);

    k_copy<<<(N0 * HID + 255) / 256, 256, 0, stream>>>(hb, x0, N0 * HID);
    k_scadd<<<(KP1 * HID + 255) / 256, 256, 0, stream>>>(hb, ub, pm0, KP1);
    gcn_u8(A0u, N0, hb, HID, U2, c2, NCLS, 0, o16);

    k_logsm<<<(N0 + 255) / 256, 256, 0, stream>>>(o16, out, N0);
}

// Round 3
// 1428.877 us; speedup vs baseline: 1.7440x; 1.7440x over previous
//
#include <hip/hip_runtime.h>
#include <math.h>
#include <stddef.h>

#define N0   4096
#define NE   131072
#define FIN  1433
#define HID  32
#define NCLS 16
#define KP1  2000
#define KP2  1000
#define KP3  500

typedef __attribute__((ext_vector_type(8))) short bf16x8;
typedef __attribute__((ext_vector_type(4))) float f32x4;

// ---------------- basic utils ----------------

__global__ __launch_bounds__(256) void k_fill0_u32(unsigned* p, size_t n) {
    size_t i = (size_t)blockIdx.x * blockDim.x + threadIdx.x;
    size_t st = (size_t)gridDim.x * blockDim.x;
    for (; i < n; i += st) p[i] = 0u;
}

__global__ __launch_bounds__(256) void k_copy(float* dst, const float* src, int n) {
    int i = blockIdx.x * blockDim.x + threadIdx.x;
    if (i < n) dst[i] = src[i];
}

// scatter edges into packed-u8 dense adjacency (exact small counts)
__global__ __launch_bounds__(256) void k_scatter(const int* ei, unsigned* A0w) {
    int e = blockIdx.x * blockDim.x + threadIdx.x;
    if (e >= NE) return;
    int r = ei[e], c = ei[NE + e];
    if (r == c) return;
    size_t idx = (size_t)r * N0 + c;
    atomicAdd(&A0w[idx >> 2], 1u << (8 * (idx & 3)));
}

// scatter into both A0 and A0^T
__global__ __launch_bounds__(256) void k_scatter2(const int* ei, unsigned* A0w, unsigned* A0Tw) {
    int e = blockIdx.x * blockDim.x + threadIdx.x;
    if (e >= NE) return;
    int r = ei[e], c = ei[NE + e];
    if (r == c) return;
    size_t idx = (size_t)r * N0 + c;
    atomicAdd(&A0w[idx >> 2], 1u << (8 * (idx & 3)));
    size_t idt = (size_t)c * N0 + r;
    atomicAdd(&A0Tw[idt >> 2], 1u << (8 * (idt & 3)));
}

// deg[i] = rowsum(A) + 2 (improved self loop), dv[i] = 1/sqrt(deg)
template <class T>
__global__ __launch_bounds__(256) void k_deg(const T* A, int n, float* dv) {
    int i = blockIdx.x;
    const T* row = A + (size_t)i * n;
    float acc = 0.f;
    for (int j = threadIdx.x; j < n; j += 256) acc += (float)row[j];
    __shared__ float red[256];
    red[threadIdx.x] = acc; __syncthreads();
    for (int off = 128; off > 0; off >>= 1) {
        if (threadIdx.x < off) red[threadIdx.x] += red[threadIdx.x + off];
        __syncthreads();
    }
    if (threadIdx.x == 0) {
        double deg = (double)red[0] + 2.0;
        dv[i] = (float)(1.0 / sqrt(deg));
    }
}

// XW[i][c] = sum_k X[i][k] * W[k][c]
__global__ __launch_bounds__(256) void k_xw(const float* X, const float* W, float* XW, int K, int NC) {
    int i = blockIdx.x;
    int c = threadIdx.x % NC, g = threadIdx.x / NC;
    int G = 256 / NC;
    const float* xr = X + (size_t)i * K;
    float acc = 0.f;
    for (int k = g; k < K; k += G) acc += xr[k] * W[(size_t)k * NC + c];
    __shared__ float red[256];
    red[threadIdx.x] = acc; __syncthreads();
    for (int off = 128; off >= NC; off >>= 1) {
        if (threadIdx.x < off) red[threadIdx.x] += red[threadIdx.x + off];
        __syncthreads();
    }
    if (threadIdx.x < NC) XW[(size_t)i * NC + threadIdx.x] = red[threadIdx.x];
}

__global__ __launch_bounds__(256) void k_scaley(const float* xw, const float* dv, float* y, int tot, int NC) {
    int i = blockIdx.x * blockDim.x + threadIdx.x;
    if (i < tot) y[i] = dv[i / NC] * xw[i];
}

// out[i][c] = dv[i]*sum_j A[i][j]*y[j][c] + 2*dv[i]*y[i][c] + b[c], optional relu
template <class T>
__global__ __launch_bounds__(256) void k_spmm(const T* A, const float* y, const float* dv,
                                              const float* bias, float* out, int n, int NC, int relu) {
    int i = blockIdx.x;
    int c = threadIdx.x % NC, g = threadIdx.x / NC;
    int G = 256 / NC;
    const T* row = A + (size_t)i * n;
    float acc = 0.f;
    for (int j = g; j < n; j += G) acc += (float)row[j] * y[(size_t)j * NC + c];
    __shared__ float red[256];
    red[threadIdx.x] = acc; __syncthreads();
    for (int off = 128; off >= NC; off >>= 1) {
        if (threadIdx.x < off) red[threadIdx.x] += red[threadIdx.x + off];
        __syncthreads();
    }
    if (threadIdx.x < NC) {
        float di = dv[i];
        float v = di * red[threadIdx.x] + 2.f * di * y[(size_t)i * NC + threadIdx.x] + bias[threadIdx.x];
        if (relu) v = fmaxf(v, 0.f);
        out[(size_t)i * NC + threadIdx.x] = v;
    }
}

// ---------------- top-k pooling ----------------

__global__ __launch_bounds__(256) void k_score(const float* x, const float* p, float* s, int n) {
    int i = blockIdx.x * blockDim.x + threadIdx.x;
    if (i >= n) return;
    float nrm = 0.f;
    for (int c = 0; c < HID; c++) nrm += p[c] * p[c];
    nrm = sqrtf(nrm);
    const float* xr = x + (size_t)i * HID;
    float d = 0.f;
    for (int c = 0; c < HID; c++) d += xr[c] * p[c];
    s[i] = tanhf(d / nrm);
}

__global__ __launch_bounds__(256) void k_rank(const float* s, int* rk, int n) {
    int i = blockIdx.x * blockDim.x + threadIdx.x;
    if (i >= n) return;
    float si = s[i];
    int r = 0;
    for (int j = 0; j < n; j++) {
        float sj = s[j];
        r += (sj > si) || (sj == si && j < i);
    }
    rk[i] = r;
}

__global__ __launch_bounds__(256) void k_perm(const int* rk, int* perm, int n, int k) {
    int i = blockIdx.x * blockDim.x + threadIdx.x;
    if (i >= n) return;
    int r = rk[i];
    if (r < k) perm[r] = i;
}

__global__ __launch_bounds__(256) void k_poolx(const float* x, const float* s, const int* perm, float* xp, int k) {
    int idx = blockIdx.x * blockDim.x + threadIdx.x;
    if (idx >= k * HID) return;
    int r = idx / HID, c = idx % HID;
    int pr = perm[r];
    xp[idx] = x[(size_t)pr * HID + c] * s[pr];
}

// ---------------- old (fp32/u8 vector) augment+pool path ----------------

template <class T>
__global__ __launch_bounds__(256) void k_gcols(const T* A, const int* perm, T* CG, int n, int kk) {
    size_t idx = (size_t)blockIdx.x * blockDim.x + threadIdx.x;
    if (idx >= (size_t)n * kk) return;
    int k = (int)(idx / kk), r2 = (int)(idx % kk);
    int pc = perm[r2];
    T v = A[(size_t)k * n + pc];
    if (k == pc) v = (T)(v + (T)1);
    CG[idx] = v;
}

template <class T>
__global__ __launch_bounds__(256) void k_gemm_pool(const T* A, const int* perm, const T* CG,
                                                   float* Ap, int n, int kk) {
    __shared__ float As[16][65];
    __shared__ float Bs[16][65];
    __shared__ int   pr[64];
    int r0 = blockIdx.y * 64, c0 = blockIdx.x * 64;
    int tx = threadIdx.x % 16, ty = threadIdx.x / 16;

    for (int t = threadIdx.x; t < 64; t += 256) {
        int rg = r0 + t;
        pr[t] = (rg < kk) ? perm[rg] : -1;
    }
    __syncthreads();

    float acc[4][4] = {};
    int cB = threadIdx.x % 64, kB = threadIdx.x / 64;

    for (int k0 = 0; k0 < n; k0 += 16) {
        for (int pass = 0; pass < 4; pass++) {
            int r = ty + pass * 16;
            int kk_ = k0 + tx;
            int prow = pr[r];
            float v = 0.f;
            if (prow >= 0 && kk_ < n) {
                v = (float)A[(size_t)prow * n + kk_];
                if (prow == kk_) v += 1.f;
            }
            As[tx][r] = v;
        }
        for (int pass = 0; pass < 4; pass++) {
            int k = kB + 4 * pass;
            int cg = c0 + cB;
            float v = 0.f;
            if (cg < kk && (k0 + k) < n) v = (float)CG[(size_t)(k0 + k) * kk + cg];
            Bs[k][cB] = v;
        }
        __syncthreads();
        for (int k = 0; k < 16; k++) {
            float a[4], b[4];
            #pragma unroll
            for (int i = 0; i < 4; i++) a[i] = As[k][ty * 4 + i];
            #pragma unroll
            for (int j = 0; j < 4; j++) b[j] = Bs[k][tx * 4 + j];
            #pragma unroll
            for (int i = 0; i < 4; i++)
                #pragma unroll
                for (int j = 0; j < 4; j++) acc[i][j] += a[i] * b[j];
        }
        __syncthreads();
    }
    for (int i = 0; i < 4; i++) {
        int rg = r0 + ty * 4 + i;
        if (rg >= kk) continue;
        for (int j = 0; j < 4; j++) {
            int cg = c0 + tx * 4 + j;
            if (cg >= kk) continue;
            Ap[(size_t)rg * kk + cg] = (rg == cg) ? 0.f : acc[i][j];
        }
    }
}

// ---------------- new MFMA augment+pool path ----------------

// 64x64 u8 tiled transpose (N0 fixed, divisible by 64)
__global__ __launch_bounds__(256) void k_tr_u8(const unsigned char* A, unsigned char* AT) {
    __shared__ unsigned char t[64][65];
    int bx = blockIdx.x * 64, by = blockIdx.y * 64;
    int tx = threadIdx.x % 16;
    int ry = threadIdx.x / 16;
    for (int p = 0; p < 4; p++) {
        int r = ry + p * 16;
        uchar4 v = *(const uchar4*)&A[(size_t)(by + r) * N0 + bx + tx * 4];
        t[r][tx * 4 + 0] = v.x; t[r][tx * 4 + 1] = v.y;
        t[r][tx * 4 + 2] = v.z; t[r][tx * 4 + 3] = v.w;
    }
    __syncthreads();
    for (int p = 0; p < 4; p++) {
        int r = ry + p * 16;
        uchar4 v;
        v.x = t[tx * 4 + 0][r]; v.y = t[tx * 4 + 1][r];
        v.z = t[tx * 4 + 2][r]; v.w = t[tx * 4 + 3][r];
        *(uchar4*)&AT[(size_t)(bx + r) * N0 + by + tx * 4] = v;
    }
}

// 32x32 f32 tiled transpose with guards
__global__ __launch_bounds__(256) void k_tr_f32(const float* A, float* AT, int n) {
    __shared__ float t[32][33];
    int bx = blockIdx.x * 32, by = blockIdx.y * 32;
    int tx = threadIdx.x % 32, ty = threadIdx.x / 32;
    for (int p = 0; p < 4; p++) {
        int r = by + ty + p * 8, c = bx + tx;
        t[ty + p * 8][tx] = (r < n && c < n) ? A[(size_t)r * n + c] : 0.f;
    }
    __syncthreads();
    for (int p = 0; p < 4; p++) {
        int r = bx + ty + p * 8, c = by + tx;
        if (r < n && c < n) AT[(size_t)r * n + c] = t[tx][ty + p * 8];
    }
}

// gather rows of (A + I) by perm into padded bf16 panel: dst[r][k], r < Mpad, k < Kpad
template <class T>
__global__ __launch_bounds__(256) void k_prep(const T* src, int n, int Kpad, const int* perm, int kk,
                                              unsigned short* dst) {
    int r = blockIdx.x;
    unsigned short* drow = dst + (size_t)r * Kpad;
    if (r >= kk) {
        for (int k = threadIdx.x; k < Kpad; k += 256) drow[k] = 0;
        return;
    }
    int pr = perm[r];
    const T* srow = src + (size_t)pr * n;
    for (int k = threadIdx.x; k < Kpad; k += 256) {
        float v = (k < n) ? (float)srow[k] : 0.f;
        if (k == pr) v += 1.f;                       // (A + I) diag; exact small ints -> bf16 exact
        drow[k] = (unsigned short)(__float_as_uint(v) >> 16);
    }
}

// C[r][c] = sum_k Abf[r][k]*Bbf[c][k]; 128x128 tile, 4 waves (each 64x64), BK=64, bf16 MFMA, fp32 acc
__global__ __launch_bounds__(256) void k_mfma_pool(const unsigned short* Abf, const unsigned short* Bbf,
                                                   float* Ap, int Kpad, int kk) {
    __shared__ short As[128 * 64];   // [row][k] bf16, XOR-swizzled
    __shared__ short Bs[128 * 64];   // [col][k] bf16, XOR-swizzled
    int r0 = blockIdx.y * 128, c0 = blockIdx.x * 128;
    int tid = threadIdx.x;
    int l = tid & 63, w = tid >> 6;
    int wm = w >> 1, wn = w & 1;     // 2x2 waves, each 64x64 output
    f32x4 acc[4][4] = {};

    for (int k0 = 0; k0 < Kpad; k0 += 64) {
        __syncthreads();
        #pragma unroll
        for (int p = 0; p < 4; p++) {
            int row = p * 32 + (tid >> 3);
            int ch  = tid & 7;
            int byte = row * 128 + ((ch * 16) ^ ((row & 7) << 4));
            bf16x8 va = *(const bf16x8*)&Abf[(size_t)(r0 + row) * Kpad + k0 + ch * 8];
            *(bf16x8*)((char*)As + byte) = va;
            bf16x8 vb = *(const bf16x8*)&Bbf[(size_t)(c0 + row) * Kpad + k0 + ch * 8];
            *(bf16x8*)((char*)Bs + byte) = vb;
        }
        __syncthreads();
        #pragma unroll
        for (int h = 0; h < 2; h++) {
            bf16x8 af[4], bfr[4];
            #pragma unroll
            for (int i = 0; i < 4; i++) {
                int row = wm * 64 + i * 16 + (l & 15);
                int byte = row * 128 + ((h * 64 + (l >> 4) * 16) ^ ((row & 7) << 4));
                af[i] = *(const bf16x8*)((const char*)As + byte);
            }
            #pragma unroll
            for (int j = 0; j < 4; j++) {
                int row = wn * 64 + j * 16 + (l & 15);
                int byte = row * 128 + ((h * 64 + (l >> 4) * 16) ^ ((row & 7) << 4));
                bfr[j] = *(const bf16x8*)((const char*)Bs + byte);
            }
            #pragma unroll
            for (int i = 0; i < 4; i++)
                #pragma unroll
                for (int j = 0; j < 4; j++)
                    acc[i][j] = __builtin_amdgcn_mfma_f32_16x16x32_bf16(af[i], bfr[j], acc[i][j], 0, 0, 0);
        }
    }
    #pragma unroll
    for (int i = 0; i < 4; i++) {
        #pragma unroll
        for (int j = 0; j < 4; j++) {
            int cg = c0 + wn * 64 + j * 16 + (l & 15);
            if (cg < kk) {
                #pragma unroll
                for (int q = 0; q < 4; q++) {
                    int rg = r0 + wm * 64 + i * 16 + (l >> 4) * 4 + q;
                    if (rg < kk) Ap[(size_t)rg * kk + cg] = (rg == cg) ? 0.f : acc[i][j][q];
                }
            }
        }
    }
}

// ---------------- up path + output ----------------

__global__ __launch_bounds__(256) void k_scadd(float* h, const float* xs, const int* perm, int k) {
    int idx = blockIdx.x * blockDim.x + threadIdx.x;
    if (idx >= k * HID) return;
    int r = idx / HID, c = idx % HID;
    h[(size_t)perm[r] * HID + c] += xs[idx];
}

__global__ __launch_bounds__(256) void k_logsm(const float* in, float* out, int n) {
    int i = blockIdx.x * blockDim.x + threadIdx.x;
    if (i >= n) return;
    const float* r = in + (size_t)i * NCLS;
    float m = -1e30f;
    for (int c = 0; c < NCLS; c++) m = fmaxf(m, r[c]);
    float sum = 0.f;
    for (int c = 0; c < NCLS; c++) sum += expf(r[c] - m);
    float ls = logf(sum);
    float* o = out + (size_t)i * NCLS;
    for (int c = 0; c < NCLS; c++) o[c] = r[c] - m - ls;
}

// ---------------- host ----------------

extern "C" void kernel_launch(void* const* d_in, const int* in_sizes, int n_in,
                              void* d_out, int out_size, void* d_ws, size_t ws_size,
                              hipStream_t stream) {
    const float* x  = (const float*)d_in[0];
    const int*   ei = (const int*)d_in[1];
    const float* W0 = (const float*)d_in[2];  const float* b0 = (const float*)d_in[3];
    const float* W1 = (const float*)d_in[4];  const float* b1 = (const float*)d_in[5];
    const float* W2 = (const float*)d_in[6];  const float* b2 = (const float*)d_in[7];
    const float* W3 = (const float*)d_in[8];  const float* b3 = (const float*)d_in[9];
    const float* U0 = (const float*)d_in[10]; const float* c0 = (const float*)d_in[11];
    const float* U1 = (const float*)d_in[12]; const float* c1 = (const float*)d_in[13];
    const float* U2 = (const float*)d_in[14]; const float* c2 = (const float*)d_in[15];
    const float* p0 = (const float*)d_in[16];
    const float* p1 = (const float*)d_in[17];
    const float* p2 = (const float*)d_in[18];
    float* out = (float*)d_out;

    char* w = (char*)d_ws;
    size_t off = 0;
    auto alloc = [&](size_t bytes) -> void* {
        void* p = w + off;
        off += (bytes + 255) / 256 * 256;
        return p;
    };
    // common buffers (both paths)
    unsigned char* A0u = (unsigned char*)alloc((size_t)N0 * N0);
    float* A1  = (float*)alloc((size_t)KP1 * KP1 * 4);
    float* A2  = (float*)alloc((size_t)KP2 * KP2 * 4);
    float* A3  = (float*)alloc((size_t)KP3 * KP3 * 4);
    void*  CG  = alloc((size_t)N0 * KP1);               // old path L0 u8 / L1 f32 use; new path L2 f32
    float* x0  = (float*)alloc((size_t)N0 * HID * 4);
    float* x1  = (float*)alloc((size_t)KP1 * HID * 4);
    float* x2  = (float*)alloc((size_t)KP2 * HID * 4);
    float* x3  = (float*)alloc((size_t)KP3 * HID * 4);
    float* xp  = (float*)alloc((size_t)KP1 * HID * 4);
    float* ua  = (float*)alloc((size_t)KP2 * HID * 4);
    float* ub  = (float*)alloc((size_t)KP1 * HID * 4);
    float* hb  = (float*)alloc((size_t)N0 * HID * 4);
    float* xw  = (float*)alloc((size_t)N0 * HID * 4);
    float* yb  = (float*)alloc((size_t)N0 * HID * 4);
    float* dv  = (float*)alloc((size_t)N0 * 4);
    float* sc  = (float*)alloc((size_t)N0 * 4);
    float* o16 = (float*)alloc((size_t)N0 * NCLS * 4);
    int*   rk  = (int*)alloc((size_t)N0 * 4);
    int*   pm0 = (int*)alloc((size_t)KP1 * 4);
    int*   pm1 = (int*)alloc((size_t)KP2 * 4);
    int*   pm2 = (int*)alloc((size_t)KP3 * 4);
    size_t common_end = off;

    // new-path extras
    unsigned char* A0T = (unsigned char*)alloc((size_t)N0 * N0);
    float*          A1T = (float*)alloc((size_t)KP1 * KP1 * 4);
    unsigned short* Abf = (unsigned short*)alloc((size_t)2048 * 4096 * 2);
    unsigned short* Bbf = (unsigned short*)alloc((size_t)2048 * 4096 * 2);
    size_t need_new = off;
    bool use_mfma = (ws_size >= need_new);
    (void)common_end; (void)in_sizes; (void)n_in; (void)out_size;

    auto gcn_u8 = [&](const unsigned char* A, int n, const float* xin, int K,
                      const float* W, const float* bias, int NC, int relu, float* outv) {
        k_deg<unsigned char><<<n, 256, 0, stream>>>(A, n, dv);
        k_xw<<<n, 256, 0, stream>>>(xin, W, xw, K, NC);
        int tot = n * NC;
        k_scaley<<<(tot + 255) / 256, 256, 0, stream>>>(xw, dv, yb, tot, NC);
        k_spmm<unsigned char><<<n, 256, 0, stream>>>(A, yb, dv, bias, outv, n, NC, relu);
    };
    auto gcn_f = [&](const float* A, int n, const float* xin, int K,
                     const float* W, const float* bias, int NC, int relu, float* outv) {
        k_deg<float><<<n, 256, 0, stream>>>(A, n, dv);
        k_xw<<<n, 256, 0, stream>>>(xin, W, xw, K, NC);
        int tot = n * NC;
        k_scaley<<<(tot + 255) / 256, 256, 0, stream>>>(xw, dv, yb, tot, NC);
        k_spmm<float><<<n, 256, 0, stream>>>(A, yb, dv, bias, outv, n, NC, relu);
    };
    auto pool = [&](const float* xin, const float* p, int n, int k, int* perm, float* xpo) {
        k_score<<<(n + 255) / 256, 256, 0, stream>>>(xin, p, sc, n);
        k_rank<<<(n + 255) / 256, 256, 0, stream>>>(sc, rk, n);
        k_perm<<<(n + 255) / 256, 256, 0, stream>>>(rk, perm, n, k);
        k_poolx<<<(k * HID + 255) / 256, 256, 0, stream>>>(xin, sc, perm, xpo, k);
    };
    auto augpool_u8 = [&](const unsigned char* A, int n, const int* perm, int kk, float* Ap) {
        size_t tot = (size_t)n * kk;
        unsigned char* cg = (unsigned char*)CG;
        k_gcols<unsigned char><<<(int)((tot + 255) / 256), 256, 0, stream>>>(A, perm, cg, n, kk);
        dim3 g((kk + 63) / 64, (kk + 63) / 64);
        k_gemm_pool<unsigned char><<<g, 256, 0, stream>>>(A, perm, cg, Ap, n, kk);
    };
    auto augpool_f = [&](const float* A, int n, const int* perm, int kk, float* Ap) {
        size_t tot = (size_t)n * kk;
        float* cg = (float*)CG;
        k_gcols<float><<<(int)((tot + 255) / 256), 256, 0, stream>>>(A, perm, cg, n, kk);
        dim3 g((kk + 63) / 64, (kk + 63) / 64);
        k_gemm_pool<float><<<g, 256, 0, stream>>>(A, perm, cg, Ap, n, kk);
    };

    if (use_mfma) {
        // build dense adjacency + transpose
        k_fill0_u32<<<2048, 256, 0, stream>>>((unsigned*)A0u, (size_t)N0 * N0 / 4);
        k_fill0_u32<<<2048, 256, 0, stream>>>((unsigned*)A0T, (size_t)N0 * N0 / 4);
        k_scatter2<<<(NE + 255) / 256, 256, 0, stream>>>(ei, (unsigned*)A0u, (unsigned*)A0T);

        // down path
        gcn_u8(A0u, N0, x, FIN, W0, b0, HID, 1, x0);
        pool(x0, p0, N0, KP1, pm0, xp);
        // L0 augpool via MFMA (exact: all values small integers)
        k_prep<unsigned char><<<2048, 256, 0, stream>>>(A0u, N0, 4096, pm0, KP1, Abf);
        k_prep<unsigned char><<<2048, 256, 0, stream>>>(A0T, N0, 4096, pm0, KP1, Bbf);
        {
            dim3 g(16, 16);
            k_mfma_pool<<<g, 256, 0, stream>>>(Abf, Bbf, A1, 4096, KP1);
        }
        gcn_f(A1, KP1, xp, HID, W1, b1, HID, 1, x1);
        k_tr_f32<<<dim3(63, 63), 256, 0, stream>>>(A1, A1T, KP1);
        pool(x1, p1, KP1, KP2, pm1, xp);
        // L1 augpool via MFMA (exact: values < 256)
        k_prep<float><<<1024, 256, 0, stream>>>(A1, KP1, 2048, pm1, KP2, Abf);
        k_prep<float><<<1024, 256, 0, stream>>>(A1T, KP1, 2048, pm1, KP2, Bbf);
        {
            dim3 g(8, 8);
            k_mfma_pool<<<g, 256, 0, stream>>>(Abf, Bbf, A2, 2048, KP2);
        }
        gcn_f(A2, KP2, xp, HID, W2, b2, HID, 1, x2);
        pool(x2, p2, KP2, KP3, pm2, xp);
        augpool_f(A2, KP2, pm2, KP3, A3);   // values may exceed 256 -> keep exact fp32 path
        gcn_f(A3, KP3, xp, HID, W3, b3, HID, 1, x3);
    } else {
        // fallback: round-2 exact fp32/u8 path
        k_fill0_u32<<<2048, 256, 0, stream>>>((unsigned*)A0u, (size_t)N0 * N0 / 4);
        k_scatter<<<(NE + 255) / 256, 256, 0, stream>>>(ei, (unsigned*)A0u);

        gcn_u8(A0u, N0, x, FIN, W0, b0, HID, 1, x0);
        pool(x0, p0, N0, KP1, pm0, xp);
        augpool_u8(A0u, N0, pm0, KP1, A1);
        gcn_f(A1, KP1, xp, HID, W1, b1, HID, 1, x1);
        pool(x1, p1, KP1, KP2, pm1, xp);
        augpool_f(A1, KP1, pm1, KP2, A2);
        gcn_f(A2, KP2, xp, HID, W2, b2, HID, 1, x2);
        pool(x2, p2, KP2, KP3, pm2, xp);
        augpool_f(A2, KP2, pm2, KP3, A3);
        gcn_f(A3, KP3, xp, HID, W3, b3, HID, 1, x3);
    }

    // up path
    k_copy<<<(KP2 * HID + 255) / 256, 256, 0, stream>>>(hb, x2, KP2 * HID);
    k_scadd<<<(KP3 * HID + 255) / 256, 256, 0, stream>>>(hb, x3, pm2, KP3);
    gcn_f(A2, KP2, hb, HID, U0, c0, HID, 1, ua);

    k_copy<<<(KP1 * HID + 255) / 256, 256, 0, stream>>>(hb, x1, KP1 * HID);
    k_scadd<<<(KP2 * HID + 255) / 256, 256, 0, stream>>>(hb, ua, pm1, KP2);
    gcn_f(A1, KP1, hb, HID, U1, c1, HID, 1, ub);

    k_copy<<<(N0 * HID + 255) / 256, 256, 0, stream>>>(hb, x0, N0 * HID);
    k_scadd<<<(KP1 * HID + 255) / 256, 256, 0, stream>>>(hb, ub, pm0, KP1);
    gcn_u8(A0u, N0, hb, HID, U2, c2, NCLS, 0, o16);

    k_logsm<<<(N0 + 255) / 256, 256, 0, stream>>>(o16, out, N0);
}

// Round 5
// 1025.640 us; speedup vs baseline: 2.4297x; 1.3932x over previous
//
#include <hip/hip_runtime.h>
#include <math.h>
#include <stddef.h>

#define N0   4096
#define NE   131072
#define FIN  1433
#define HID  32
#define NCLS 16
#define KP1  2000
#define KP2  1000
#define KP3  500

typedef __attribute__((ext_vector_type(8))) short bf16x8;
typedef __attribute__((ext_vector_type(4))) float f32x4;

// ---------------- basic utils ----------------

__global__ __launch_bounds__(256) void k_fill0_u32(unsigned* p, size_t n) {
    size_t i = (size_t)blockIdx.x * blockDim.x + threadIdx.x;
    size_t st = (size_t)gridDim.x * blockDim.x;
    for (; i < n; i += st) p[i] = 0u;
}

__global__ __launch_bounds__(256) void k_copy(float* dst, const float* src, int n) {
    int i = blockIdx.x * blockDim.x + threadIdx.x;
    if (i < n) dst[i] = src[i];
}

// scatter into A0 and A0^T (packed u8 byte-lane atomics; exact small counts)
__global__ __launch_bounds__(256) void k_scatter2(const int* ei, unsigned* A0w, unsigned* A0Tw) {
    int e = blockIdx.x * blockDim.x + threadIdx.x;
    if (e >= NE) return;
    int r = ei[e], c = ei[NE + e];
    if (r == c) return;
    size_t idx = (size_t)r * N0 + c;
    atomicAdd(&A0w[idx >> 2], 1u << (8 * (idx & 3)));
    size_t idt = (size_t)c * N0 + r;
    atomicAdd(&A0Tw[idt >> 2], 1u << (8 * (idt & 3)));
}

// vectorized deg for u8 adjacency (n multiple of 16): dv[i]=1/sqrt(rowsum+2)
__global__ __launch_bounds__(256) void k_deg8(const unsigned char* A, int n, float* dv) {
    int i = blockIdx.x;
    const unsigned char* row = A + (size_t)i * n;
    unsigned accu = 0;
    for (int j = threadIdx.x * 16; j < n; j += 256 * 16) {
        uint4 w = *(const uint4*)&row[j];
        #pragma unroll
        for (int q = 0; q < 4; q++) {
            unsigned v = ((const unsigned*)&w)[q];
            accu += (v & 0xff) + ((v >> 8) & 0xff) + ((v >> 16) & 0xff) + (v >> 24);
        }
    }
    __shared__ float red[256];
    red[threadIdx.x] = (float)accu; __syncthreads();
    for (int off = 128; off > 0; off >>= 1) {
        if (threadIdx.x < off) red[threadIdx.x] += red[threadIdx.x + off];
        __syncthreads();
    }
    if (threadIdx.x == 0) dv[i] = (float)(1.0 / sqrt((double)red[0] + 2.0));
}

// vectorized deg for f32 adjacency (n multiple of 4); entries are exact integers
__global__ __launch_bounds__(256) void k_degf(const float* A, int n, float* dv) {
    int i = blockIdx.x;
    const float* row = A + (size_t)i * n;
    float acc = 0.f;
    for (int j = threadIdx.x * 4; j < n; j += 256 * 4) {
        float4 w = *(const float4*)&row[j];
        acc += w.x + w.y + w.z + w.w;
    }
    __shared__ float red[256];
    red[threadIdx.x] = acc; __syncthreads();
    for (int off = 128; off > 0; off >>= 1) {
        if (threadIdx.x < off) red[threadIdx.x] += red[threadIdx.x + off];
        __syncthreads();
    }
    if (threadIdx.x == 0) dv[i] = (float)(1.0 / sqrt((double)red[0] + 2.0));
}

// XW[i][c] = sum_k X[i][k] * W[k][c]
__global__ __launch_bounds__(256) void k_xw(const float* X, const float* W, float* XW, int K, int NC) {
    int i = blockIdx.x;
    int c = threadIdx.x % NC, g = threadIdx.x / NC;
    int G = 256 / NC;
    const float* xr = X + (size_t)i * K;
    float acc = 0.f;
    for (int k = g; k < K; k += G) acc += xr[k] * W[(size_t)k * NC + c];
    __shared__ float red[256];
    red[threadIdx.x] = acc; __syncthreads();
    for (int off = 128; off >= NC; off >>= 1) {
        if (threadIdx.x < off) red[threadIdx.x] += red[threadIdx.x + off];
        __syncthreads();
    }
    if (threadIdx.x < NC) XW[(size_t)i * NC + threadIdx.x] = red[threadIdx.x];
}

__global__ __launch_bounds__(256) void k_scaley(const float* xw, const float* dv, float* y, int tot, int NC) {
    int i = blockIdx.x * blockDim.x + threadIdx.x;
    if (i < tot) y[i] = dv[i / NC] * xw[i];
}

// ---------------- tiled split-K aggregation: part[s][i][c] = sum_{k in chunk s} A[i][k]*y[k][c] ----------------
// grid (ceil(M/64), S); 256 threads; A staged transposed in LDS as f32, y tile in LDS.

template <class T, int NC>
__global__ __launch_bounds__(256) void k_agg(const T* __restrict__ A, const float* __restrict__ y,
                                             float* __restrict__ part, int n, int M, int chunk) {
    constexpr int G   = 256 / NC;   // row groups
    constexpr int RPT = 64 / G;     // rows per thread: 8 (NC=32) or 4 (NC=16)
    __shared__ float At[64][72];
    __shared__ float ys[64][NC];
    int r0 = blockIdx.x * 64;
    int s  = blockIdx.y;
    int k_begin = s * chunk;
    int k_end   = min(k_begin + chunk, n);
    int tid = threadIdx.x;
    int c = tid % NC, g = tid / NC;
    int r = tid & 63, kq = tid >> 6;          // staging coords: row r, k-quarter kq
    bool row_ok = (r0 + r) < M;
    float acc[RPT] = {};

    for (int k0 = k_begin; k0 < k_end; k0 += 64) {
        __syncthreads();
        // ---- stage A tile (transposed, f32) ----
        if constexpr (sizeof(T) == 1) {
            uint4 w = {0u, 0u, 0u, 0u};
            if (row_ok) w = *(const uint4*)&A[(size_t)(r0 + r) * n + k0 + kq * 16];
            #pragma unroll
            for (int j = 0; j < 16; j++) {
                int kl = kq * 16 + j;
                unsigned b = (((const unsigned*)&w)[j >> 2] >> (8 * (j & 3))) & 0xffu;
                At[kl][r] = (k0 + kl < k_end) ? (float)b : 0.f;
            }
        } else {
            #pragma unroll
            for (int q = 0; q < 4; q++) {
                int kl = kq * 16 + q * 4;
                float4 w = {0.f, 0.f, 0.f, 0.f};
                if (row_ok) w = *(const float4*)&A[(size_t)(r0 + r) * n + k0 + kl];
                At[kl + 0][r] = (k0 + kl + 0 < k_end) ? w.x : 0.f;
                At[kl + 1][r] = (k0 + kl + 1 < k_end) ? w.y : 0.f;
                At[kl + 2][r] = (k0 + kl + 2 < k_end) ? w.z : 0.f;
                At[kl + 3][r] = (k0 + kl + 3 < k_end) ? w.w : 0.f;
            }
        }
        // ---- stage y tile ----
        constexpr int NF4 = 64 * NC / 4;
        #pragma unroll
        for (int f = 0; f < NF4 / 256; f++) {
            int fi = tid + f * 256;
            int k = fi / (NC / 4), cb = fi % (NC / 4);
            float4 w = *(const float4*)&y[(size_t)(k0 + k) * NC + cb * 4];
            *(float4*)&ys[k][cb * 4] = w;
        }
        __syncthreads();
        // ---- compute ----
        for (int k = 0; k < 64; k++) {
            float yv = ys[k][c];
            #pragma unroll
            for (int i = 0; i < RPT; i += 4) {
                float4 a = *(const float4*)&At[k][g * RPT + i];
                acc[i + 0] += a.x * yv;
                acc[i + 1] += a.y * yv;
                acc[i + 2] += a.z * yv;
                acc[i + 3] += a.w * yv;
            }
        }
    }
    #pragma unroll
    for (int i = 0; i < RPT; i++) {
        int row = r0 + g * RPT + i;
        if (row < M) part[((size_t)s * M + row) * NC + c] = acc[i];
    }
}

// epilogue: out[i][c] = dv[i]*sum_s part + 2dv[i]*y[i][c] + bias[c], optional relu
template <int NC>
__global__ __launch_bounds__(256) void k_aggfin(const float* __restrict__ part, int S,
                                                const float* __restrict__ y, const float* __restrict__ dvv,
                                                const float* __restrict__ bias, float* __restrict__ out,
                                                int M, int relu) {
    int idx = blockIdx.x * blockDim.x + threadIdx.x;
    if (idx >= M * NC) return;
    int i = idx / NC, c = idx % NC;
    float sum = 0.f;
    for (int s = 0; s < S; s++) sum += part[(size_t)s * M * NC + idx];
    float di = dvv[i];
    float v = di * sum + 2.f * di * y[idx] + bias[c];
    if (relu) v = fmaxf(v, 0.f);
    out[idx] = v;
}

// ---------------- top-k pooling ----------------

__global__ __launch_bounds__(256) void k_score(const float* x, const float* p, float* s, int n) {
    int i = blockIdx.x * blockDim.x + threadIdx.x;
    if (i >= n) return;
    float nrm = 0.f;
    for (int c = 0; c < HID; c++) nrm += p[c] * p[c];
    nrm = sqrtf(nrm);
    const float* xr = x + (size_t)i * HID;
    float d = 0.f;
    for (int c = 0; c < HID; c++) d += xr[c] * p[c];
    s[i] = tanhf(d / nrm);
}

__global__ __launch_bounds__(256) void k_rank(const float* s, int* rk, int n) {
    int i = blockIdx.x * blockDim.x + threadIdx.x;
    if (i >= n) return;
    float si = s[i];
    int r = 0;
    for (int j = 0; j < n; j++) {
        float sj = s[j];
        r += (sj > si) || (sj == si && j < i);
    }
    rk[i] = r;
}

__global__ __launch_bounds__(256) void k_perm(const int* rk, int* perm, int n, int k) {
    int i = blockIdx.x * blockDim.x + threadIdx.x;
    if (i >= n) return;
    int r = rk[i];
    if (r < k) perm[r] = i;
}

__global__ __launch_bounds__(256) void k_poolx(const float* x, const float* s, const int* perm, float* xp, int k) {
    int idx = blockIdx.x * blockDim.x + threadIdx.x;
    if (idx >= k * HID) return;
    int r = idx / HID, c = idx % HID;
    int pr = perm[r];
    xp[idx] = x[(size_t)pr * HID + c] * s[pr];
}

// ---------------- fp32 augment+pool path (level 2 only; values can exceed bf16-exact range) ----------------

template <class T>
__global__ __launch_bounds__(256) void k_gcols(const T* A, const int* perm, T* CG, int n, int kk) {
    size_t idx = (size_t)blockIdx.x * blockDim.x + threadIdx.x;
    if (idx >= (size_t)n * kk) return;
    int k = (int)(idx / kk), r2 = (int)(idx % kk);
    int pc = perm[r2];
    T v = A[(size_t)k * n + pc];
    if (k == pc) v = (T)(v + (T)1);
    CG[idx] = v;
}

template <class T>
__global__ __launch_bounds__(256) void k_gemm_pool(const T* A, const int* perm, const T* CG,
                                                   float* Ap, int n, int kk) {
    __shared__ float As[16][65];
    __shared__ float Bs[16][65];
    __shared__ int   pr[64];
    int r0 = blockIdx.y * 64, c0 = blockIdx.x * 64;
    int tx = threadIdx.x % 16, ty = threadIdx.x / 16;

    for (int t = threadIdx.x; t < 64; t += 256) {
        int rg = r0 + t;
        pr[t] = (rg < kk) ? perm[rg] : -1;
    }
    __syncthreads();

    float acc[4][4] = {};
    int cB = threadIdx.x % 64, kB = threadIdx.x / 64;

    for (int k0 = 0; k0 < n; k0 += 16) {
        for (int pass = 0; pass < 4; pass++) {
            int rr = ty + pass * 16;
            int kk_ = k0 + tx;
            int prow = pr[rr];
            float v = 0.f;
            if (prow >= 0 && kk_ < n) {
                v = (float)A[(size_t)prow * n + kk_];
                if (prow == kk_) v += 1.f;
            }
            As[tx][rr] = v;
        }
        for (int pass = 0; pass < 4; pass++) {
            int k = kB + 4 * pass;
            int cg = c0 + cB;
            float v = 0.f;
            if (cg < kk && (k0 + k) < n) v = (float)CG[(size_t)(k0 + k) * kk + cg];
            Bs[k][cB] = v;
        }
        __syncthreads();
        for (int k = 0; k < 16; k++) {
            float a[4], b[4];
            #pragma unroll
            for (int i = 0; i < 4; i++) a[i] = As[k][ty * 4 + i];
            #pragma unroll
            for (int j = 0; j < 4; j++) b[j] = Bs[k][tx * 4 + j];
            #pragma unroll
            for (int i = 0; i < 4; i++)
                #pragma unroll
                for (int j = 0; j < 4; j++) acc[i][j] += a[i] * b[j];
        }
        __syncthreads();
    }
    for (int i = 0; i < 4; i++) {
        int rg = r0 + ty * 4 + i;
        if (rg >= kk) continue;
        for (int j = 0; j < 4; j++) {
            int cg = c0 + tx * 4 + j;
            if (cg >= kk) continue;
            Ap[(size_t)rg * kk + cg] = (rg == cg) ? 0.f : acc[i][j];
        }
    }
}

// ---------------- MFMA augment+pool path (levels 0,1; bf16-exact integer values) ----------------

// 32x32 f32 tiled transpose with guards
__global__ __launch_bounds__(256) void k_tr_f32(const float* A, float* AT, int n) {
    __shared__ float t[32][33];
    int bx = blockIdx.x * 32, by = blockIdx.y * 32;
    int tx = threadIdx.x % 32, ty = threadIdx.x / 32;
    for (int p = 0; p < 4; p++) {
        int r = by + ty + p * 8, c = bx + tx;
        t[ty + p * 8][tx] = (r < n && c < n) ? A[(size_t)r * n + c] : 0.f;
    }
    __syncthreads();
    for (int p = 0; p < 4; p++) {
        int r = bx + ty + p * 8, c = by + tx;
        if (r < n && c < n) AT[(size_t)r * n + c] = t[tx][ty + p * 8];
    }
}

// vectorized u8 -> bf16 row-gather of (A+I) by perm (n == Kpad == 4096)
__global__ __launch_bounds__(256) void k_prep8(const unsigned char* src, int n, int Kpad,
                                               const int* perm, int kk, unsigned short* dst) {
    int r = blockIdx.x;
    unsigned short* drow = dst + (size_t)r * Kpad;
    if (r >= kk) {
        ushort4 z = {0, 0, 0, 0};
        for (int k = threadIdx.x * 4; k < Kpad; k += 1024) *(ushort4*)&drow[k] = z;
        return;
    }
    int pr = perm[r];
    const unsigned char* srow = src + (size_t)pr * n;
    for (int k0 = threadIdx.x * 16; k0 < n; k0 += 4096) {
        uint4 w = *(const uint4*)&srow[k0];
        #pragma unroll
        for (int q = 0; q < 4; q++) {
            ushort4 o;
            #pragma unroll
            for (int j = 0; j < 4; j++) {
                unsigned b = (((const unsigned*)&w)[q] >> (8 * j)) & 0xffu;
                float v = (float)b + ((k0 + q * 4 + j == pr) ? 1.f : 0.f);
                ((unsigned short*)&o)[j] = (unsigned short)(__float_as_uint(v) >> 16);
            }
            *(ushort4*)&drow[k0 + q * 4] = o;
        }
    }
}

// f32 -> bf16 row-gather of (A+I) by perm, padded
__global__ __launch_bounds__(256) void k_prepf(const float* src, int n, int Kpad,
                                               const int* perm, int kk, unsigned short* dst) {
    int r = blockIdx.x;
    unsigned short* drow = dst + (size_t)r * Kpad;
    if (r >= kk) {
        for (int k = threadIdx.x; k < Kpad; k += 256) drow[k] = 0;
        return;
    }
    int pr = perm[r];
    const float* srow = src + (size_t)pr * n;
    for (int k = threadIdx.x; k < Kpad; k += 256) {
        float v = (k < n) ? srow[k] : 0.f;
        if (k == pr) v += 1.f;
        drow[k] = (unsigned short)(__float_as_uint(v) >> 16);
    }
}

// C[r][c] = sum_k Abf[r][k]*Bbf[c][k]; 128x128 tile, 4 waves, BK=64, bf16 MFMA, fp32 acc (exact ints)
__global__ __launch_bounds__(256) void k_mfma_pool(const unsigned short* Abf, const unsigned short* Bbf,
                                                   float* Ap, int Kpad, int kk) {
    __shared__ short As[128 * 64];
    __shared__ short Bs[128 * 64];
    int r0 = blockIdx.y * 128, c0 = blockIdx.x * 128;
    int tid = threadIdx.x;
    int l = tid & 63, w = tid >> 6;
    int wm = w >> 1, wn = w & 1;
    f32x4 acc[4][4] = {};

    for (int k0 = 0; k0 < Kpad; k0 += 64) {
        __syncthreads();
        #pragma unroll
        for (int p = 0; p < 4; p++) {
            int row = p * 32 + (tid >> 3);
            int ch  = tid & 7;
            int byte = row * 128 + ((ch * 16) ^ ((row & 7) << 4));
            bf16x8 va = *(const bf16x8*)&Abf[(size_t)(r0 + row) * Kpad + k0 + ch * 8];
            *(bf16x8*)((char*)As + byte) = va;
            bf16x8 vb = *(const bf16x8*)&Bbf[(size_t)(c0 + row) * Kpad + k0 + ch * 8];
            *(bf16x8*)((char*)Bs + byte) = vb;
        }
        __syncthreads();
        #pragma unroll
        for (int h = 0; h < 2; h++) {
            bf16x8 af[4], bfr[4];
            #pragma unroll
            for (int i = 0; i < 4; i++) {
                int row = wm * 64 + i * 16 + (l & 15);
                int byte = row * 128 + ((h * 64 + (l >> 4) * 16) ^ ((row & 7) << 4));
                af[i] = *(const bf16x8*)((const char*)As + byte);
            }
            #pragma unroll
            for (int j = 0; j < 4; j++) {
                int row = wn * 64 + j * 16 + (l & 15);
                int byte = row * 128 + ((h * 64 + (l >> 4) * 16) ^ ((row & 7) << 4));
                bfr[j] = *(const bf16x8*)((const char*)Bs + byte);
            }
            #pragma unroll
            for (int i = 0; i < 4; i++)
                #pragma unroll
                for (int j = 0; j < 4; j++)
                    acc[i][j] = __builtin_amdgcn_mfma_f32_16x16x32_bf16(af[i], bfr[j], acc[i][j], 0, 0, 0);
        }
    }
    #pragma unroll
    for (int i = 0; i < 4; i++) {
        #pragma unroll
        for (int j = 0; j < 4; j++) {
            int cg = c0 + wn * 64 + j * 16 + (l & 15);
            if (cg < kk) {
                #pragma unroll
                for (int q = 0; q < 4; q++) {
                    int rg = r0 + wm * 64 + i * 16 + (l >> 4) * 4 + q;
                    if (rg < kk) Ap[(size_t)rg * kk + cg] = (rg == cg) ? 0.f : acc[i][j][q];
                }
            }
        }
    }
}

// ---------------- up path + output ----------------

__global__ __launch_bounds__(256) void k_scadd(float* h, const float* xs, const int* perm, int k) {
    int idx = blockIdx.x * blockDim.x + threadIdx.x;
    if (idx >= k * HID) return;
    int r = idx / HID, c = idx % HID;
    h[(size_t)perm[r] * HID + c] += xs[idx];
}

__global__ __launch_bounds__(256) void k_logsm(const float* in, float* out, int n) {
    int i = blockIdx.x * blockDim.x + threadIdx.x;
    if (i >= n) return;
    const float* r = in + (size_t)i * NCLS;
    float m = -1e30f;
    for (int c = 0; c < NCLS; c++) m = fmaxf(m, r[c]);
    float sum = 0.f;
    for (int c = 0; c < NCLS; c++) sum += expf(r[c] - m);
    float ls = logf(sum);
    float* o = out + (size_t)i * NCLS;
    for (int c = 0; c < NCLS; c++) o[c] = r[c] - m - ls;
}

// ---------------- host ----------------

extern "C" void kernel_launch(void* const* d_in, const int* in_sizes, int n_in,
                              void* d_out, int out_size, void* d_ws, size_t ws_size,
                              hipStream_t stream) {
    const float* x  = (const float*)d_in[0];
    const int*   ei = (const int*)d_in[1];
    const float* W0 = (const float*)d_in[2];  const float* b0 = (const float*)d_in[3];
    const float* W1 = (const float*)d_in[4];  const float* b1 = (const float*)d_in[5];
    const float* W2 = (const float*)d_in[6];  const float* b2 = (const float*)d_in[7];
    const float* W3 = (const float*)d_in[8];  const float* b3 = (const float*)d_in[9];
    const float* U0 = (const float*)d_in[10]; const float* c0 = (const float*)d_in[11];
    const float* U1 = (const float*)d_in[12]; const float* c1 = (const float*)d_in[13];
    const float* U2 = (const float*)d_in[14]; const float* c2 = (const float*)d_in[15];
    const float* p0 = (const float*)d_in[16];
    const float* p1 = (const float*)d_in[17];
    const float* p2 = (const float*)d_in[18];
    float* out = (float*)d_out;

    char* w = (char*)d_ws;
    size_t off = 0;
    auto alloc = [&](size_t bytes) -> void* {
        void* p = w + off;
        off += (bytes + 255) / 256 * 256;
        return p;
    };
    unsigned char* A0u = (unsigned char*)alloc((size_t)N0 * N0);
    unsigned char* A0T = (unsigned char*)alloc((size_t)N0 * N0);
    float* A1  = (float*)alloc((size_t)KP1 * KP1 * 4);
    float* A1T = (float*)alloc((size_t)KP1 * KP1 * 4);
    float* A2  = (float*)alloc((size_t)KP2 * KP2 * 4);
    float* A3  = (float*)alloc((size_t)KP3 * KP3 * 4);
    float* CG  = (float*)alloc((size_t)KP2 * KP3 * 4);
    unsigned short* Abf = (unsigned short*)alloc((size_t)2048 * 4096 * 2);
    unsigned short* Bbf = (unsigned short*)alloc((size_t)2048 * 4096 * 2);
    float* part = (float*)alloc((size_t)4 * N0 * HID * 4);   // max over levels: 524288 f32
    float* x0  = (float*)alloc((size_t)N0 * HID * 4);
    float* x1  = (float*)alloc((size_t)KP1 * HID * 4);
    float* x2  = (float*)alloc((size_t)KP2 * HID * 4);
    float* x3  = (float*)alloc((size_t)KP3 * HID * 4);
    float* xp  = (float*)alloc((size_t)KP1 * HID * 4);
    float* ua  = (float*)alloc((size_t)KP2 * HID * 4);
    float* ub  = (float*)alloc((size_t)KP1 * HID * 4);
    float* hb  = (float*)alloc((size_t)N0 * HID * 4);
    float* xw  = (float*)alloc((size_t)N0 * HID * 4);
    float* yb  = (float*)alloc((size_t)N0 * HID * 4);
    float* dv0 = (float*)alloc((size_t)N0 * 4);
    float* dv1 = (float*)alloc((size_t)KP1 * 4);
    float* dv2 = (float*)alloc((size_t)KP2 * 4);
    float* dv3 = (float*)alloc((size_t)KP3 * 4);
    float* sc  = (float*)alloc((size_t)N0 * 4);
    float* o16 = (float*)alloc((size_t)N0 * NCLS * 4);
    int*   rk  = (int*)alloc((size_t)N0 * 4);
    int*   pm0 = (int*)alloc((size_t)KP1 * 4);
    int*   pm1 = (int*)alloc((size_t)KP2 * 4);
    int*   pm2 = (int*)alloc((size_t)KP3 * 4);
    (void)ws_size; (void)in_sizes; (void)n_in; (void)out_size;

    // gcn layer with u8 adjacency (NC = 32 or 16)
    auto gcn_u8_32 = [&](const unsigned char* A, int n, const float* xin, int K, const float* W,
                         const float* bias, const float* dvv, int relu, float* outv, int S, int chunk) {
        k_xw<<<n, 256, 0, stream>>>(xin, W, xw, K, 32);
        k_scaley<<<(n * 32 + 255) / 256, 256, 0, stream>>>(xw, dvv, yb, n * 32, 32);
        dim3 g((n + 63) / 64, S);
        k_agg<unsigned char, 32><<<g, 256, 0, stream>>>(A, yb, part, n, n, chunk);
        k_aggfin<32><<<(n * 32 + 255) / 256, 256, 0, stream>>>(part, S, yb, dvv, bias, outv, n, relu);
    };
    auto gcn_u8_16 = [&](const unsigned char* A, int n, const float* xin, int K, const float* W,
                         const float* bias, const float* dvv, int relu, float* outv, int S, int chunk) {
        k_xw<<<n, 256, 0, stream>>>(xin, W, xw, K, 16);
        k_scaley<<<(n * 16 + 255) / 256, 256, 0, stream>>>(xw, dvv, yb, n * 16, 16);
        dim3 g((n + 63) / 64, S);
        k_agg<unsigned char, 16><<<g, 256, 0, stream>>>(A, yb, part, n, n, chunk);
        k_aggfin<16><<<(n * 16 + 255) / 256, 256, 0, stream>>>(part, S, yb, dvv, bias, outv, n, relu);
    };
    auto gcn_f = [&](const float* A, int n, const float* xin, int K, const float* W,
                     const float* bias, const float* dvv, int relu, float* outv, int S, int chunk) {
        k_xw<<<n, 256, 0, stream>>>(xin, W, xw, K, 32);
        k_scaley<<<(n * 32 + 255) / 256, 256, 0, stream>>>(xw, dvv, yb, n * 32, 32);
        dim3 g((n + 63) / 64, S);
        k_agg<float, 32><<<g, 256, 0, stream>>>(A, yb, part, n, n, chunk);
        k_aggfin<32><<<(n * 32 + 255) / 256, 256, 0, stream>>>(part, S, yb, dvv, bias, outv, n, relu);
    };
    auto pool = [&](const float* xin, const float* p, int n, int k, int* perm, float* xpo) {
        k_score<<<(n + 255) / 256, 256, 0, stream>>>(xin, p, sc, n);
        k_rank<<<(n + 255) / 256, 256, 0, stream>>>(sc, rk, n);
        k_perm<<<(n + 255) / 256, 256, 0, stream>>>(rk, perm, n, k);
        k_poolx<<<(k * HID + 255) / 256, 256, 0, stream>>>(xin, sc, perm, xpo, k);
    };

    // build dense adjacency + transpose
    k_fill0_u32<<<2048, 256, 0, stream>>>((unsigned*)A0u, (size_t)N0 * N0 / 4);
    k_fill0_u32<<<2048, 256, 0, stream>>>((unsigned*)A0T, (size_t)N0 * N0 / 4);
    k_scatter2<<<(NE + 255) / 256, 256, 0, stream>>>(ei, (unsigned*)A0u, (unsigned*)A0T);

    // degrees (once per level)
    k_deg8<<<N0, 256, 0, stream>>>(A0u, N0, dv0);

    // ---- down path ----
    gcn_u8_32(A0u, N0, x, FIN, W0, b0, dv0, 1, x0, 4, 1024);
    pool(x0, p0, N0, KP1, pm0, xp);

    k_prep8<<<2048, 256, 0, stream>>>(A0u, N0, 4096, pm0, KP1, Abf);
    k_prep8<<<2048, 256, 0, stream>>>(A0T, N0, 4096, pm0, KP1, Bbf);
    k_mfma_pool<<<dim3(16, 16), 256, 0, stream>>>(Abf, Bbf, A1, 4096, KP1);

    k_degf<<<KP1, 256, 0, stream>>>(A1, KP1, dv1);
    gcn_f(A1, KP1, xp, HID, W1, b1, dv1, 1, x1, 8, 256);
    k_tr_f32<<<dim3(63, 63), 256, 0, stream>>>(A1, A1T, KP1);
    pool(x1, p1, KP1, KP2, pm1, xp);

    k_prepf<<<1024, 256, 0, stream>>>(A1, KP1, 2048, pm1, KP2, Abf);
    k_prepf<<<1024, 256, 0, stream>>>(A1T, KP1, 2048, pm1, KP2, Bbf);
    k_mfma_pool<<<dim3(8, 8), 256, 0, stream>>>(Abf, Bbf, A2, 2048, KP2);

    k_degf<<<KP2, 256, 0, stream>>>(A2, KP2, dv2);
    gcn_f(A2, KP2, xp, HID, W2, b2, dv2, 1, x2, 16, 64);
    pool(x2, p2, KP2, KP3, pm2, xp);

    // L2 augment+pool stays exact fp32 (values may exceed bf16-exact range)
    {
        size_t tot = (size_t)KP2 * KP3;
        k_gcols<float><<<(int)((tot + 255) / 256), 256, 0, stream>>>(A2, pm2, CG, KP2, KP3);
        k_gemm_pool<float><<<dim3(8, 8), 256, 0, stream>>>(A2, pm2, CG, A3, KP2, KP3);
    }
    k_degf<<<KP3, 256, 0, stream>>>(A3, KP3, dv3);
    gcn_f(A3, KP3, xp, HID, W3, b3, dv3, 1, x3, 8, 64);

    // ---- up path ----
    k_copy<<<(KP2 * HID + 255) / 256, 256, 0, stream>>>(hb, x2, KP2 * HID);
    k_scadd<<<(KP3 * HID + 255) / 256, 256, 0, stream>>>(hb, x3, pm2, KP3);
    gcn_f(A2, KP2, hb, HID, U0, c0, dv2, 1, ua, 16, 64);

    k_copy<<<(KP1 * HID + 255) / 256, 256, 0, stream>>>(hb, x1, KP1 * HID);
    k_scadd<<<(KP2 * HID + 255) / 256, 256, 0, stream>>>(hb, ua, pm1, KP2);
    gcn_f(A1, KP1, hb, HID, U1, c1, dv1, 1, ub, 8, 256);

    k_copy<<<(N0 * HID + 255) / 256, 256, 0, stream>>>(hb, x0, N0 * HID);
    k_scadd<<<(KP1 * HID + 255) / 256, 256, 0, stream>>>(hb, ub, pm0, KP1);
    gcn_u8_16(A0u, N0, hb, HID, U2, c2, dv0, 0, o16, 4, 1024);

    k_logsm<<<(N0 + 255) / 256, 256, 0, stream>>>(o16, out, N0);
}

// Round 6
// 877.990 us; speedup vs baseline: 2.8383x; 1.1682x over previous
//
#include <hip/hip_runtime.h>
#include <math.h>
#include <stddef.h>

#define N0   4096
#define NE   131072
#define FIN  1433
#define HID  32
#define NCLS 16
#define KP1  2000
#define KP2  1000
#define KP3  500

typedef __attribute__((ext_vector_type(8))) short bf16x8;
typedef __attribute__((ext_vector_type(4))) float f32x4;

// ---------------- basic utils ----------------

__global__ __launch_bounds__(256) void k_fill0_u32(unsigned* p, size_t n) {
    size_t i = (size_t)blockIdx.x * blockDim.x + threadIdx.x;
    size_t st = (size_t)gridDim.x * blockDim.x;
    for (; i < n; i += st) p[i] = 0u;
}

__global__ __launch_bounds__(256) void k_copy(float* dst, const float* src, int n) {
    int i = blockIdx.x * blockDim.x + threadIdx.x;
    if (i < n) dst[i] = src[i];
}

// scatter into A0 and A0^T (packed u8 byte-lane atomics; exact small counts)
__global__ __launch_bounds__(256) void k_scatter2(const int* ei, unsigned* A0w, unsigned* A0Tw) {
    int e = blockIdx.x * blockDim.x + threadIdx.x;
    if (e >= NE) return;
    int r = ei[e], c = ei[NE + e];
    if (r == c) return;
    size_t idx = (size_t)r * N0 + c;
    atomicAdd(&A0w[idx >> 2], 1u << (8 * (idx & 3)));
    size_t idt = (size_t)c * N0 + r;
    atomicAdd(&A0Tw[idt >> 2], 1u << (8 * (idt & 3)));
}

// vectorized deg for u8 adjacency (n multiple of 16): dv[i]=1/sqrt(rowsum+2)
__global__ __launch_bounds__(256) void k_deg8(const unsigned char* A, int n, float* dv) {
    int i = blockIdx.x;
    const unsigned char* row = A + (size_t)i * n;
    unsigned accu = 0;
    for (int j = threadIdx.x * 16; j < n; j += 256 * 16) {
        uint4 w = *(const uint4*)&row[j];
        #pragma unroll
        for (int q = 0; q < 4; q++) {
            unsigned v = ((const unsigned*)&w)[q];
            accu += (v & 0xff) + ((v >> 8) & 0xff) + ((v >> 16) & 0xff) + (v >> 24);
        }
    }
    __shared__ float red[256];
    red[threadIdx.x] = (float)accu; __syncthreads();
    for (int off = 128; off > 0; off >>= 1) {
        if (threadIdx.x < off) red[threadIdx.x] += red[threadIdx.x + off];
        __syncthreads();
    }
    if (threadIdx.x == 0) dv[i] = (float)(1.0 / sqrt((double)red[0] + 2.0));
}

// vectorized deg for f32 adjacency (n multiple of 4); entries are exact integers
__global__ __launch_bounds__(256) void k_degf(const float* A, int n, float* dv) {
    int i = blockIdx.x;
    const float* row = A + (size_t)i * n;
    float acc = 0.f;
    for (int j = threadIdx.x * 4; j < n; j += 256 * 4) {
        float4 w = *(const float4*)&row[j];
        acc += w.x + w.y + w.z + w.w;
    }
    __shared__ float red[256];
    red[threadIdx.x] = acc; __syncthreads();
    for (int off = 128; off > 0; off >>= 1) {
        if (threadIdx.x < off) red[threadIdx.x] += red[threadIdx.x + off];
        __syncthreads();
    }
    if (threadIdx.x == 0) dv[i] = (float)(1.0 / sqrt((double)red[0] + 2.0));
}

// XW[i][c] = sum_k X[i][k] * W[k][c]
__global__ __launch_bounds__(256) void k_xw(const float* X, const float* W, float* XW, int K, int NC) {
    int i = blockIdx.x;
    int c = threadIdx.x % NC, g = threadIdx.x / NC;
    int G = 256 / NC;
    const float* xr = X + (size_t)i * K;
    float acc = 0.f;
    for (int k = g; k < K; k += G) acc += xr[k] * W[(size_t)k * NC + c];
    __shared__ float red[256];
    red[threadIdx.x] = acc; __syncthreads();
    for (int off = 128; off >= NC; off >>= 1) {
        if (threadIdx.x < off) red[threadIdx.x] += red[threadIdx.x + off];
        __syncthreads();
    }
    if (threadIdx.x < NC) XW[(size_t)i * NC + threadIdx.x] = red[threadIdx.x];
}

__global__ __launch_bounds__(256) void k_scaley(const float* xw, const float* dv, float* y, int tot, int NC) {
    int i = blockIdx.x * blockDim.x + threadIdx.x;
    if (i < tot) y[i] = dv[i / NC] * xw[i];
}

// ---------------- tiled split-K aggregation: part[s][i][c] = sum_{k in chunk s} A[i][k]*y[k][c] ----------------

template <class T, int NC>
__global__ __launch_bounds__(256) void k_agg(const T* __restrict__ A, const float* __restrict__ y,
                                             float* __restrict__ part, int n, int M, int chunk) {
    constexpr int G   = 256 / NC;
    constexpr int RPT = 64 / G;
    __shared__ float At[64][72];
    __shared__ float ys[64][NC];
    int r0 = blockIdx.x * 64;
    int s  = blockIdx.y;
    int k_begin = s * chunk;
    int k_end   = min(k_begin + chunk, n);
    int tid = threadIdx.x;
    int c = tid % NC, g = tid / NC;
    int r = tid & 63, kq = tid >> 6;
    bool row_ok = (r0 + r) < M;
    float acc[RPT] = {};

    for (int k0 = k_begin; k0 < k_end; k0 += 64) {
        __syncthreads();
        if constexpr (sizeof(T) == 1) {
            uint4 w = {0u, 0u, 0u, 0u};
            if (row_ok) w = *(const uint4*)&A[(size_t)(r0 + r) * n + k0 + kq * 16];
            #pragma unroll
            for (int j = 0; j < 16; j++) {
                int kl = kq * 16 + j;
                unsigned b = (((const unsigned*)&w)[j >> 2] >> (8 * (j & 3))) & 0xffu;
                At[kl][r] = (k0 + kl < k_end) ? (float)b : 0.f;
            }
        } else {
            #pragma unroll
            for (int q = 0; q < 4; q++) {
                int kl = kq * 16 + q * 4;
                float4 w = {0.f, 0.f, 0.f, 0.f};
                if (row_ok) w = *(const float4*)&A[(size_t)(r0 + r) * n + k0 + kl];
                At[kl + 0][r] = (k0 + kl + 0 < k_end) ? w.x : 0.f;
                At[kl + 1][r] = (k0 + kl + 1 < k_end) ? w.y : 0.f;
                At[kl + 2][r] = (k0 + kl + 2 < k_end) ? w.z : 0.f;
                At[kl + 3][r] = (k0 + kl + 3 < k_end) ? w.w : 0.f;
            }
        }
        constexpr int NF4 = 64 * NC / 4;
        #pragma unroll
        for (int f = 0; f < NF4 / 256; f++) {
            int fi = tid + f * 256;
            int k = fi / (NC / 4), cb = fi % (NC / 4);
            float4 w = *(const float4*)&y[(size_t)(k0 + k) * NC + cb * 4];
            *(float4*)&ys[k][cb * 4] = w;
        }
        __syncthreads();
        for (int k = 0; k < 64; k++) {
            float yv = ys[k][c];
            #pragma unroll
            for (int i = 0; i < RPT; i += 4) {
                float4 a = *(const float4*)&At[k][g * RPT + i];
                acc[i + 0] += a.x * yv;
                acc[i + 1] += a.y * yv;
                acc[i + 2] += a.z * yv;
                acc[i + 3] += a.w * yv;
            }
        }
    }
    #pragma unroll
    for (int i = 0; i < RPT; i++) {
        int row = r0 + g * RPT + i;
        if (row < M) part[((size_t)s * M + row) * NC + c] = acc[i];
    }
}

template <int NC>
__global__ __launch_bounds__(256) void k_aggfin(const float* __restrict__ part, int S,
                                                const float* __restrict__ y, const float* __restrict__ dvv,
                                                const float* __restrict__ bias, float* __restrict__ out,
                                                int M, int relu) {
    int idx = blockIdx.x * blockDim.x + threadIdx.x;
    if (idx >= M * NC) return;
    int i = idx / NC, c = idx % NC;
    float sum = 0.f;
    for (int s = 0; s < S; s++) sum += part[(size_t)s * M * NC + idx];
    float di = dvv[i];
    float v = di * sum + 2.f * di * y[idx] + bias[c];
    if (relu) v = fmaxf(v, 0.f);
    out[idx] = v;
}

// ---------------- top-k pooling ----------------

__global__ __launch_bounds__(256) void k_score(const float* x, const float* p, float* s, int n) {
    int i = blockIdx.x * blockDim.x + threadIdx.x;
    if (i >= n) return;
    float nrm = 0.f;
    for (int c = 0; c < HID; c++) nrm += p[c] * p[c];
    nrm = sqrtf(nrm);
    const float* xr = x + (size_t)i * HID;
    float d = 0.f;
    for (int c = 0; c < HID; c++) d += xr[c] * p[c];
    s[i] = tanhf(d / nrm);
}

__global__ __launch_bounds__(256) void k_rank(const float* s, int* rk, int n) {
    int i = blockIdx.x * blockDim.x + threadIdx.x;
    if (i >= n) return;
    float si = s[i];
    int r = 0;
    for (int j = 0; j < n; j++) {
        float sj = s[j];
        r += (sj > si) || (sj == si && j < i);
    }
    rk[i] = r;
}

__global__ __launch_bounds__(256) void k_perm(const int* rk, int* perm, int n, int k) {
    int i = blockIdx.x * blockDim.x + threadIdx.x;
    if (i >= n) return;
    int r = rk[i];
    if (r < k) perm[r] = i;
}

__global__ __launch_bounds__(256) void k_poolx(const float* x, const float* s, const int* perm, float* xp, int k) {
    int idx = blockIdx.x * blockDim.x + threadIdx.x;
    if (idx >= k * HID) return;
    int r = idx / HID, c = idx % HID;
    int pr = perm[r];
    xp[idx] = x[(size_t)pr * HID + c] * s[pr];
}

// ---------------- fp32 augment+pool path (level 2; split-K for occupancy) ----------------

template <class T>
__global__ __launch_bounds__(256) void k_gcols(const T* A, const int* perm, T* CG, int n, int kk) {
    size_t idx = (size_t)blockIdx.x * blockDim.x + threadIdx.x;
    if (idx >= (size_t)n * kk) return;
    int k = (int)(idx / kk), r2 = (int)(idx % kk);
    int pc = perm[r2];
    T v = A[(size_t)k * n + pc];
    if (k == pc) v = (T)(v + (T)1);
    CG[idx] = v;
}

// split-K partial GEMM: part[s][r][c] = sum_{k in chunk s} (A[perm[r]][k]+I) * CG[k][c]
__global__ __launch_bounds__(256) void k_gemm_pool_sk(const float* A, const int* perm, const float* CG,
                                                      float* part, int n, int kk, int chunk) {
    __shared__ float As[16][65];
    __shared__ float Bs[16][65];
    __shared__ int   pr[64];
    int r0 = blockIdx.y * 64, c0 = blockIdx.x * 64;
    int s  = blockIdx.z;
    int k_begin = s * chunk;
    int k_end   = min(k_begin + chunk, n);
    int tx = threadIdx.x % 16, ty = threadIdx.x / 16;

    for (int t = threadIdx.x; t < 64; t += 256) {
        int rg = r0 + t;
        pr[t] = (rg < kk) ? perm[rg] : -1;
    }
    __syncthreads();

    float acc[4][4] = {};
    int cB = threadIdx.x % 64, kB = threadIdx.x / 64;

    for (int k0 = k_begin; k0 < k_end; k0 += 16) {
        for (int pass = 0; pass < 4; pass++) {
            int rr = ty + pass * 16;
            int kk_ = k0 + tx;
            int prow = pr[rr];
            float v = 0.f;
            if (prow >= 0 && kk_ < k_end) {
                v = A[(size_t)prow * n + kk_];
                if (prow == kk_) v += 1.f;
            }
            As[tx][rr] = v;
        }
        for (int pass = 0; pass < 4; pass++) {
            int k = kB + 4 * pass;
            int cg = c0 + cB;
            float v = 0.f;
            if (cg < kk && (k0 + k) < k_end) v = CG[(size_t)(k0 + k) * kk + cg];
            Bs[k][cB] = v;
        }
        __syncthreads();
        for (int k = 0; k < 16; k++) {
            float a[4], b[4];
            #pragma unroll
            for (int i = 0; i < 4; i++) a[i] = As[k][ty * 4 + i];
            #pragma unroll
            for (int j = 0; j < 4; j++) b[j] = Bs[k][tx * 4 + j];
            #pragma unroll
            for (int i = 0; i < 4; i++)
                #pragma unroll
                for (int j = 0; j < 4; j++) acc[i][j] += a[i] * b[j];
        }
        __syncthreads();
    }
    for (int i = 0; i < 4; i++) {
        int rg = r0 + ty * 4 + i;
        if (rg >= kk) continue;
        for (int j = 0; j < 4; j++) {
            int cg = c0 + tx * 4 + j;
            if (cg >= kk) continue;
            part[((size_t)s * kk + rg) * kk + cg] = acc[i][j];
        }
    }
}

// reduce split-K partials, zero diagonal
__global__ __launch_bounds__(256) void k_gpfin(const float* __restrict__ part, int S, float* __restrict__ Ap, int kk) {
    int idx = blockIdx.x * blockDim.x + threadIdx.x;
    if (idx >= kk * kk) return;
    int rg = idx / kk, cg = idx % kk;
    float sum = 0.f;
    for (int s = 0; s < S; s++) sum += part[(size_t)s * kk * kk + idx];
    Ap[idx] = (rg == cg) ? 0.f : sum;
}

// ---------------- MFMA augment+pool path (levels 0,1; bf16-exact integer values) ----------------

// 32x32 f32 tiled transpose with guards
__global__ __launch_bounds__(256) void k_tr_f32(const float* A, float* AT, int n) {
    __shared__ float t[32][33];
    int bx = blockIdx.x * 32, by = blockIdx.y * 32;
    int tx = threadIdx.x % 32, ty = threadIdx.x / 32;
    for (int p = 0; p < 4; p++) {
        int r = by + ty + p * 8, c = bx + tx;
        t[ty + p * 8][tx] = (r < n && c < n) ? A[(size_t)r * n + c] : 0.f;
    }
    __syncthreads();
    for (int p = 0; p < 4; p++) {
        int r = bx + ty + p * 8, c = by + tx;
        if (r < n && c < n) AT[(size_t)r * n + c] = t[tx][ty + p * 8];
    }
}

// vectorized u8 -> bf16 row-gather of (A+I) by perm (n == Kpad == 4096)
__global__ __launch_bounds__(256) void k_prep8(const unsigned char* src, int n, int Kpad,
                                               const int* perm, int kk, unsigned short* dst) {
    int r = blockIdx.x;
    unsigned short* drow = dst + (size_t)r * Kpad;
    if (r >= kk) {
        ushort4 z = {0, 0, 0, 0};
        for (int k = threadIdx.x * 4; k < Kpad; k += 1024) *(ushort4*)&drow[k] = z;
        return;
    }
    int pr = perm[r];
    const unsigned char* srow = src + (size_t)pr * n;
    for (int k0 = threadIdx.x * 16; k0 < n; k0 += 4096) {
        uint4 w = *(const uint4*)&srow[k0];
        #pragma unroll
        for (int q = 0; q < 4; q++) {
            ushort4 o;
            #pragma unroll
            for (int j = 0; j < 4; j++) {
                unsigned b = (((const unsigned*)&w)[q] >> (8 * j)) & 0xffu;
                float v = (float)b + ((k0 + q * 4 + j == pr) ? 1.f : 0.f);
                ((unsigned short*)&o)[j] = (unsigned short)(__float_as_uint(v) >> 16);
            }
            *(ushort4*)&drow[k0 + q * 4] = o;
        }
    }
}

// f32 -> bf16 row-gather of (A+I) by perm, padded
__global__ __launch_bounds__(256) void k_prepf(const float* src, int n, int Kpad,
                                               const int* perm, int kk, unsigned short* dst) {
    int r = blockIdx.x;
    unsigned short* drow = dst + (size_t)r * Kpad;
    if (r >= kk) {
        for (int k = threadIdx.x; k < Kpad; k += 256) drow[k] = 0;
        return;
    }
    int pr = perm[r];
    const float* srow = src + (size_t)pr * n;
    for (int k = threadIdx.x; k < Kpad; k += 256) {
        float v = (k < n) ? srow[k] : 0.f;
        if (k == pr) v += 1.f;
        drow[k] = (unsigned short)(__float_as_uint(v) >> 16);
    }
}

// C[r][c] = sum_k Abf[r][k]*Bbf[c][k]; 128x128 tile, 4 waves, BK=64, bf16 MFMA, fp32 acc (exact ints)
__global__ __launch_bounds__(256) void k_mfma_pool(const unsigned short* Abf, const unsigned short* Bbf,
                                                   float* Ap, int Kpad, int kk) {
    __shared__ short As[128 * 64];
    __shared__ short Bs[128 * 64];
    int r0 = blockIdx.y * 128, c0 = blockIdx.x * 128;
    int tid = threadIdx.x;
    int l = tid & 63, w = tid >> 6;
    int wm = w >> 1, wn = w & 1;
    f32x4 acc[4][4] = {};

    for (int k0 = 0; k0 < Kpad; k0 += 64) {
        __syncthreads();
        #pragma unroll
        for (int p = 0; p < 4; p++) {
            int row = p * 32 + (tid >> 3);
            int ch  = tid & 7;
            int byte = row * 128 + ((ch * 16) ^ ((row & 7) << 4));
            bf16x8 va = *(const bf16x8*)&Abf[(size_t)(r0 + row) * Kpad + k0 + ch * 8];
            *(bf16x8*)((char*)As + byte) = va;
            bf16x8 vb = *(const bf16x8*)&Bbf[(size_t)(c0 + row) * Kpad + k0 + ch * 8];
            *(bf16x8*)((char*)Bs + byte) = vb;
        }
        __syncthreads();
        #pragma unroll
        for (int h = 0; h < 2; h++) {
            bf16x8 af[4], bfr[4];
            #pragma unroll
            for (int i = 0; i < 4; i++) {
                int row = wm * 64 + i * 16 + (l & 15);
                int byte = row * 128 + ((h * 64 + (l >> 4) * 16) ^ ((row & 7) << 4));
                af[i] = *(const bf16x8*)((const char*)As + byte);
            }
            #pragma unroll
            for (int j = 0; j < 4; j++) {
                int row = wn * 64 + j * 16 + (l & 15);
                int byte = row * 128 + ((h * 64 + (l >> 4) * 16) ^ ((row & 7) << 4));
                bfr[j] = *(const bf16x8*)((const char*)Bs + byte);
            }
            #pragma unroll
            for (int i = 0; i < 4; i++)
                #pragma unroll
                for (int j = 0; j < 4; j++)
                    acc[i][j] = __builtin_amdgcn_mfma_f32_16x16x32_bf16(af[i], bfr[j], acc[i][j], 0, 0, 0);
        }
    }
    #pragma unroll
    for (int i = 0; i < 4; i++) {
        #pragma unroll
        for (int j = 0; j < 4; j++) {
            int cg = c0 + wn * 64 + j * 16 + (l & 15);
            if (cg < kk) {
                #pragma unroll
                for (int q = 0; q < 4; q++) {
                    int rg = r0 + wm * 64 + i * 16 + (l >> 4) * 4 + q;
                    if (rg < kk) Ap[(size_t)rg * kk + cg] = (rg == cg) ? 0.f : acc[i][j][q];
                }
            }
        }
    }
}

// ---------------- up path + output ----------------

__global__ __launch_bounds__(256) void k_scadd(float* h, const float* xs, const int* perm, int k) {
    int idx = blockIdx.x * blockDim.x + threadIdx.x;
    if (idx >= k * HID) return;
    int r = idx / HID, c = idx % HID;
    h[(size_t)perm[r] * HID + c] += xs[idx];
}

__global__ __launch_bounds__(256) void k_logsm(const float* in, float* out, int n) {
    int i = blockIdx.x * blockDim.x + threadIdx.x;
    if (i >= n) return;
    const float* r = in + (size_t)i * NCLS;
    float m = -1e30f;
    for (int c = 0; c < NCLS; c++) m = fmaxf(m, r[c]);
    float sum = 0.f;
    for (int c = 0; c < NCLS; c++) sum += expf(r[c] - m);
    float ls = logf(sum);
    float* o = out + (size_t)i * NCLS;
    for (int c = 0; c < NCLS; c++) o[c] = r[c] - m - ls;
}

// ---------------- host ----------------

extern "C" void kernel_launch(void* const* d_in, const int* in_sizes, int n_in,
                              void* d_out, int out_size, void* d_ws, size_t ws_size,
                              hipStream_t stream) {
    const float* x  = (const float*)d_in[0];
    const int*   ei = (const int*)d_in[1];
    const float* W0 = (const float*)d_in[2];  const float* b0 = (const float*)d_in[3];
    const float* W1 = (const float*)d_in[4];  const float* b1 = (const float*)d_in[5];
    const float* W2 = (const float*)d_in[6];  const float* b2 = (const float*)d_in[7];
    const float* W3 = (const float*)d_in[8];  const float* b3 = (const float*)d_in[9];
    const float* U0 = (const float*)d_in[10]; const float* c0 = (const float*)d_in[11];
    const float* U1 = (const float*)d_in[12]; const float* c1 = (const float*)d_in[13];
    const float* U2 = (const float*)d_in[14]; const float* c2 = (const float*)d_in[15];
    const float* p0 = (const float*)d_in[16];
    const float* p1 = (const float*)d_in[17];
    const float* p2 = (const float*)d_in[18];
    float* out = (float*)d_out;

    char* w = (char*)d_ws;
    size_t off = 0;
    auto alloc = [&](size_t bytes) -> void* {
        void* p = w + off;
        off += (bytes + 255) / 256 * 256;
        return p;
    };
    unsigned char* A0u = (unsigned char*)alloc((size_t)N0 * N0);
    unsigned char* A0T = (unsigned char*)alloc((size_t)N0 * N0);
    float* A1  = (float*)alloc((size_t)KP1 * KP1 * 4);
    float* A1T = (float*)alloc((size_t)KP1 * KP1 * 4);
    float* A2  = (float*)alloc((size_t)KP2 * KP2 * 4);
    float* A3  = (float*)alloc((size_t)KP3 * KP3 * 4);
    float* CG  = (float*)alloc((size_t)KP2 * KP3 * 4);
    unsigned short* Abf = (unsigned short*)alloc((size_t)2048 * 4096 * 2);
    unsigned short* Bbf = (unsigned short*)alloc((size_t)2048 * 4096 * 2);
    float* part = (float*)alloc((size_t)4 * N0 * HID * 4);
    float* x0  = (float*)alloc((size_t)N0 * HID * 4);
    float* x1  = (float*)alloc((size_t)KP1 * HID * 4);
    float* x2  = (float*)alloc((size_t)KP2 * HID * 4);
    float* x3  = (float*)alloc((size_t)KP3 * HID * 4);
    float* xp  = (float*)alloc((size_t)KP1 * HID * 4);
    float* ua  = (float*)alloc((size_t)KP2 * HID * 4);
    float* ub  = (float*)alloc((size_t)KP1 * HID * 4);
    float* hb  = (float*)alloc((size_t)N0 * HID * 4);
    float* xw  = (float*)alloc((size_t)N0 * HID * 4);
    float* yb  = (float*)alloc((size_t)N0 * HID * 4);
    float* dv0 = (float*)alloc((size_t)N0 * 4);
    float* dv1 = (float*)alloc((size_t)KP1 * 4);
    float* dv2 = (float*)alloc((size_t)KP2 * 4);
    float* dv3 = (float*)alloc((size_t)KP3 * 4);
    float* sc  = (float*)alloc((size_t)N0 * 4);
    float* o16 = (float*)alloc((size_t)N0 * NCLS * 4);
    int*   rk  = (int*)alloc((size_t)N0 * 4);
    int*   pm0 = (int*)alloc((size_t)KP1 * 4);
    int*   pm1 = (int*)alloc((size_t)KP2 * 4);
    int*   pm2 = (int*)alloc((size_t)KP3 * 4);
    (void)ws_size; (void)in_sizes; (void)n_in; (void)out_size;

    auto gcn_u8_32 = [&](const unsigned char* A, int n, const float* xin, int K, const float* W,
                         const float* bias, const float* dvv, int relu, float* outv, int S, int chunk) {
        k_xw<<<n, 256, 0, stream>>>(xin, W, xw, K, 32);
        k_scaley<<<(n * 32 + 255) / 256, 256, 0, stream>>>(xw, dvv, yb, n * 32, 32);
        dim3 g((n + 63) / 64, S);
        k_agg<unsigned char, 32><<<g, 256, 0, stream>>>(A, yb, part, n, n, chunk);
        k_aggfin<32><<<(n * 32 + 255) / 256, 256, 0, stream>>>(part, S, yb, dvv, bias, outv, n, relu);
    };
    auto gcn_u8_16 = [&](const unsigned char* A, int n, const float* xin, int K, const float* W,
                         const float* bias, const float* dvv, int relu, float* outv, int S, int chunk) {
        k_xw<<<n, 256, 0, stream>>>(xin, W, xw, K, 16);
        k_scaley<<<(n * 16 + 255) / 256, 256, 0, stream>>>(xw, dvv, yb, n * 16, 16);
        dim3 g((n + 63) / 64, S);
        k_agg<unsigned char, 16><<<g, 256, 0, stream>>>(A, yb, part, n, n, chunk);
        k_aggfin<16><<<(n * 16 + 255) / 256, 256, 0, stream>>>(part, S, yb, dvv, bias, outv, n, relu);
    };
    auto gcn_f = [&](const float* A, int n, const float* xin, int K, const float* W,
                     const float* bias, const float* dvv, int relu, float* outv, int S, int chunk) {
        k_xw<<<n, 256, 0, stream>>>(xin, W, xw, K, 32);
        k_scaley<<<(n * 32 + 255) / 256, 256, 0, stream>>>(xw, dvv, yb, n * 32, 32);
        dim3 g((n + 63) / 64, S);
        k_agg<float, 32><<<g, 256, 0, stream>>>(A, yb, part, n, n, chunk);
        k_aggfin<32><<<(n * 32 + 255) / 256, 256, 0, stream>>>(part, S, yb, dvv, bias, outv, n, relu);
    };
    auto pool = [&](const float* xin, const float* p, int n, int k, int* perm, float* xpo) {
        k_score<<<(n + 255) / 256, 256, 0, stream>>>(xin, p, sc, n);
        k_rank<<<(n + 255) / 256, 256, 0, stream>>>(sc, rk, n);
        k_perm<<<(n + 255) / 256, 256, 0, stream>>>(rk, perm, n, k);
        k_poolx<<<(k * HID + 255) / 256, 256, 0, stream>>>(xin, sc, perm, xpo, k);
    };

    // build dense adjacency + transpose
    k_fill0_u32<<<2048, 256, 0, stream>>>((unsigned*)A0u, (size_t)N0 * N0 / 4);
    k_fill0_u32<<<2048, 256, 0, stream>>>((unsigned*)A0T, (size_t)N0 * N0 / 4);
    k_scatter2<<<(NE + 255) / 256, 256, 0, stream>>>(ei, (unsigned*)A0u, (unsigned*)A0T);

    // degrees (once per level)
    k_deg8<<<N0, 256, 0, stream>>>(A0u, N0, dv0);

    // ---- down path ----
    gcn_u8_32(A0u, N0, x, FIN, W0, b0, dv0, 1, x0, 4, 1024);
    pool(x0, p0, N0, KP1, pm0, xp);

    k_prep8<<<2048, 256, 0, stream>>>(A0u, N0, 4096, pm0, KP1, Abf);
    k_prep8<<<2048, 256, 0, stream>>>(A0T, N0, 4096, pm0, KP1, Bbf);
    k_mfma_pool<<<dim3(16, 16), 256, 0, stream>>>(Abf, Bbf, A1, 4096, KP1);

    k_degf<<<KP1, 256, 0, stream>>>(A1, KP1, dv1);
    gcn_f(A1, KP1, xp, HID, W1, b1, dv1, 1, x1, 8, 256);
    k_tr_f32<<<dim3(63, 63), 256, 0, stream>>>(A1, A1T, KP1);
    pool(x1, p1, KP1, KP2, pm1, xp);

    k_prepf<<<1024, 256, 0, stream>>>(A1, KP1, 2048, pm1, KP2, Abf);
    k_prepf<<<1024, 256, 0, stream>>>(A1T, KP1, 2048, pm1, KP2, Bbf);
    k_mfma_pool<<<dim3(8, 8), 256, 0, stream>>>(Abf, Bbf, A2, 2048, KP2);

    k_degf<<<KP2, 256, 0, stream>>>(A2, KP2, dv2);
    gcn_f(A2, KP2, xp, HID, W2, b2, dv2, 1, x2, 16, 64);
    pool(x2, p2, KP2, KP3, pm2, xp);

    // L2 augment+pool: exact fp32, split-K (S=16) for occupancy; partials reuse Abf (idle here)
    {
        size_t tot = (size_t)KP2 * KP3;
        k_gcols<float><<<(int)((tot + 255) / 256), 256, 0, stream>>>(A2, pm2, CG, KP2, KP3);
        float* pbuf = (float*)Abf;   // 16 MB needed (16*500*500*4B), Abf has 16.8 MB
        k_gemm_pool_sk<<<dim3(8, 8, 16), 256, 0, stream>>>(A2, pm2, CG, pbuf, KP2, KP3, 64);
        k_gpfin<<<(KP3 * KP3 + 255) / 256, 256, 0, stream>>>(pbuf, 16, A3, KP3);
    }
    k_degf<<<KP3, 256, 0, stream>>>(A3, KP3, dv3);
    gcn_f(A3, KP3, xp, HID, W3, b3, dv3, 1, x3, 8, 64);

    // ---- up path ----
    k_copy<<<(KP2 * HID + 255) / 256, 256, 0, stream>>>(hb, x2, KP2 * HID);
    k_scadd<<<(KP3 * HID + 255) / 256, 256, 0, stream>>>(hb, x3, pm2, KP3);
    gcn_f(A2, KP2, hb, HID, U0, c0, dv2, 1, ua, 16, 64);

    k_copy<<<(KP1 * HID + 255) / 256, 256, 0, stream>>>(hb, x1, KP1 * HID);
    k_scadd<<<(KP2 * HID + 255) / 256, 256, 0, stream>>>(hb, ua, pm1, KP2);
    gcn_f(A1, KP1, hb, HID, U1, c1, dv1, 1, ub, 8, 256);

    k_copy<<<(N0 * HID + 255) / 256, 256, 0, stream>>>(hb, x0, N0 * HID);
    k_scadd<<<(KP1 * HID + 255) / 256, 256, 0, stream>>>(hb, ub, pm0, KP1);
    gcn_u8_16(A0u, N0, hb, HID, U2, c2, dv0, 0, o16, 4, 1024);

    k_logsm<<<(N0 + 255) / 256, 256, 0, stream>>>(o16, out, N0);
}

// Round 7
// 607.430 us; speedup vs baseline: 4.1025x; 1.4454x over previous
//
#include <hip/hip_runtime.h>
#include <math.h>
#include <stddef.h>

#define N0   4096
#define NE   131072
#define FIN  1433
#define HID  32
#define NCLS 16
#define KP1  2000
#define KP2  1000
#define KP3  500
#define RCH  512

typedef __attribute__((ext_vector_type(8))) short bf16x8;
typedef __attribute__((ext_vector_type(4))) float f32x4;

// ---------------- basic utils ----------------

__global__ __launch_bounds__(256) void k_fill0_u32(unsigned* p, size_t n) {
    size_t i = (size_t)blockIdx.x * blockDim.x + threadIdx.x;
    size_t st = (size_t)gridDim.x * blockDim.x;
    for (; i < n; i += st) p[i] = 0u;
}

__global__ __launch_bounds__(256) void k_copy(float* dst, const float* src, int n) {
    int i = blockIdx.x * blockDim.x + threadIdx.x;
    if (i < n) dst[i] = src[i];
}

// scatter into A0 and A0^T (packed u8 byte-lane atomics; exact small counts)
__global__ __launch_bounds__(256) void k_scatter2(const int* ei, unsigned* A0w, unsigned* A0Tw) {
    int e = blockIdx.x * blockDim.x + threadIdx.x;
    if (e >= NE) return;
    int r = ei[e], c = ei[NE + e];
    if (r == c) return;
    size_t idx = (size_t)r * N0 + c;
    atomicAdd(&A0w[idx >> 2], 1u << (8 * (idx & 3)));
    size_t idt = (size_t)c * N0 + r;
    atomicAdd(&A0Tw[idt >> 2], 1u << (8 * (idt & 3)));
}

// vectorized deg for u8 adjacency (n multiple of 16): dv[i]=1/sqrt(rowsum+2)
__global__ __launch_bounds__(256) void k_deg8(const unsigned char* A, int n, float* dv) {
    int i = blockIdx.x;
    const unsigned char* row = A + (size_t)i * n;
    unsigned accu = 0;
    for (int j = threadIdx.x * 16; j < n; j += 256 * 16) {
        uint4 w = *(const uint4*)&row[j];
        #pragma unroll
        for (int q = 0; q < 4; q++) {
            unsigned v = ((const unsigned*)&w)[q];
            accu += (v & 0xff) + ((v >> 8) & 0xff) + ((v >> 16) & 0xff) + (v >> 24);
        }
    }
    __shared__ float red[256];
    red[threadIdx.x] = (float)accu; __syncthreads();
    for (int off = 128; off > 0; off >>= 1) {
        if (threadIdx.x < off) red[threadIdx.x] += red[threadIdx.x + off];
        __syncthreads();
    }
    if (threadIdx.x == 0) dv[i] = (float)(1.0 / sqrt((double)red[0] + 2.0));
}

// vectorized deg for f32 adjacency (n multiple of 4); entries are exact integers
__global__ __launch_bounds__(256) void k_degf(const float* A, int n, float* dv) {
    int i = blockIdx.x;
    const float* row = A + (size_t)i * n;
    float acc = 0.f;
    for (int j = threadIdx.x * 4; j < n; j += 256 * 4) {
        float4 w = *(const float4*)&row[j];
        acc += w.x + w.y + w.z + w.w;
    }
    __shared__ float red[256];
    red[threadIdx.x] = acc; __syncthreads();
    for (int off = 128; off > 0; off >>= 1) {
        if (threadIdx.x < off) red[threadIdx.x] += red[threadIdx.x + off];
        __syncthreads();
    }
    if (threadIdx.x == 0) dv[i] = (float)(1.0 / sqrt((double)red[0] + 2.0));
}

// XW[i][c] = sum_k X[i][k] * W[k][c]
__global__ __launch_bounds__(256) void k_xw(const float* X, const float* W, float* XW, int K, int NC) {
    int i = blockIdx.x;
    int c = threadIdx.x % NC, g = threadIdx.x / NC;
    int G = 256 / NC;
    const float* xr = X + (size_t)i * K;
    float acc = 0.f;
    for (int k = g; k < K; k += G) acc += xr[k] * W[(size_t)k * NC + c];
    __shared__ float red[256];
    red[threadIdx.x] = acc; __syncthreads();
    for (int off = 128; off >= NC; off >>= 1) {
        if (threadIdx.x < off) red[threadIdx.x] += red[threadIdx.x + off];
        __syncthreads();
    }
    if (threadIdx.x < NC) XW[(size_t)i * NC + threadIdx.x] = red[threadIdx.x];
}

__global__ __launch_bounds__(256) void k_scaley(const float* xw, const float* dv, float* y, int tot, int NC) {
    int i = blockIdx.x * blockDim.x + threadIdx.x;
    if (i < tot) y[i] = dv[i / NC] * xw[i];
}

// ---------------- tiled split-K aggregation: part[s][i][c] = sum_{k in chunk s} A[i][k]*y[k][c] ----------------

template <class T, int NC>
__global__ __launch_bounds__(256) void k_agg(const T* __restrict__ A, const float* __restrict__ y,
                                             float* __restrict__ part, int n, int M, int chunk) {
    constexpr int G   = 256 / NC;
    constexpr int RPT = 64 / G;
    __shared__ float At[64][72];
    __shared__ float ys[64][NC];
    int r0 = blockIdx.x * 64;
    int s  = blockIdx.y;
    int k_begin = s * chunk;
    int k_end   = min(k_begin + chunk, n);
    int tid = threadIdx.x;
    int c = tid % NC, g = tid / NC;
    int r = tid & 63, kq = tid >> 6;
    bool row_ok = (r0 + r) < M;
    float acc[RPT] = {};

    for (int k0 = k_begin; k0 < k_end; k0 += 64) {
        __syncthreads();
        if constexpr (sizeof(T) == 1) {
            uint4 w = {0u, 0u, 0u, 0u};
            if (row_ok) w = *(const uint4*)&A[(size_t)(r0 + r) * n + k0 + kq * 16];
            #pragma unroll
            for (int j = 0; j < 16; j++) {
                int kl = kq * 16 + j;
                unsigned b = (((const unsigned*)&w)[j >> 2] >> (8 * (j & 3))) & 0xffu;
                At[kl][r] = (k0 + kl < k_end) ? (float)b : 0.f;
            }
        } else {
            #pragma unroll
            for (int q = 0; q < 4; q++) {
                int kl = kq * 16 + q * 4;
                float4 w = {0.f, 0.f, 0.f, 0.f};
                if (row_ok) w = *(const float4*)&A[(size_t)(r0 + r) * n + k0 + kl];
                At[kl + 0][r] = (k0 + kl + 0 < k_end) ? w.x : 0.f;
                At[kl + 1][r] = (k0 + kl + 1 < k_end) ? w.y : 0.f;
                At[kl + 2][r] = (k0 + kl + 2 < k_end) ? w.z : 0.f;
                At[kl + 3][r] = (k0 + kl + 3 < k_end) ? w.w : 0.f;
            }
        }
        constexpr int NF4 = 64 * NC / 4;
        #pragma unroll
        for (int f = 0; f < NF4 / 256; f++) {
            int fi = tid + f * 256;
            int k = fi / (NC / 4), cb = fi % (NC / 4);
            float4 w = *(const float4*)&y[(size_t)(k0 + k) * NC + cb * 4];
            *(float4*)&ys[k][cb * 4] = w;
        }
        __syncthreads();
        for (int k = 0; k < 64; k++) {
            float yv = ys[k][c];
            #pragma unroll
            for (int i = 0; i < RPT; i += 4) {
                float4 a = *(const float4*)&At[k][g * RPT + i];
                acc[i + 0] += a.x * yv;
                acc[i + 1] += a.y * yv;
                acc[i + 2] += a.z * yv;
                acc[i + 3] += a.w * yv;
            }
        }
    }
    #pragma unroll
    for (int i = 0; i < RPT; i++) {
        int row = r0 + g * RPT + i;
        if (row < M) part[((size_t)s * M + row) * NC + c] = acc[i];
    }
}

template <int NC>
__global__ __launch_bounds__(256) void k_aggfin(const float* __restrict__ part, int S,
                                                const float* __restrict__ y, const float* __restrict__ dvv,
                                                const float* __restrict__ bias, float* __restrict__ out,
                                                int M, int relu) {
    int idx = blockIdx.x * blockDim.x + threadIdx.x;
    if (idx >= M * NC) return;
    int i = idx / NC, c = idx % NC;
    float sum = 0.f;
    for (int s = 0; s < S; s++) sum += part[(size_t)s * M * NC + idx];
    float di = dvv[i];
    float v = di * sum + 2.f * di * y[idx] + bias[c];
    if (relu) v = fmaxf(v, 0.f);
    out[idx] = v;
}

// ---------------- top-k pooling ----------------

__global__ __launch_bounds__(256) void k_score(const float* x, const float* p, float* s, int n) {
    int i = blockIdx.x * blockDim.x + threadIdx.x;
    if (i >= n) return;
    float nrm = 0.f;
    for (int c = 0; c < HID; c++) nrm += p[c] * p[c];
    nrm = sqrtf(nrm);
    const float* xr = x + (size_t)i * HID;
    float d = 0.f;
    for (int c = 0; c < HID; c++) d += xr[c] * p[c];
    s[i] = tanhf(d / nrm);
}

// split-j LDS-staged rank: rk[i] += #{j in chunk : s[j] > s[i] or (s[j]==s[i] and j<i)}
// grid (ceil(n/256), ceil(n/RCH)); rk must be zeroed first. Integer atomics -> exact.
__global__ __launch_bounds__(256) void k_rank2(const float* __restrict__ s, int* __restrict__ rk, int n) {
    __shared__ float sj[RCH];
    int i  = blockIdx.x * 256 + threadIdx.x;
    int jb = blockIdx.y * RCH;
    int len = min(jb + RCH, n) - jb;
    for (int j = threadIdx.x * 4; j < len; j += 1024)
        *(float4*)&sj[j] = *(const float4*)&s[jb + j];
    __syncthreads();
    if (i >= n) return;
    float si = s[i];
    int r = 0;
    for (int j = 0; j < len; j += 4) {
        float4 v = *(const float4*)&sj[j];
        int jg = jb + j;
        r += (v.x > si) || (v.x == si && (jg + 0) < i);
        r += (v.y > si) || (v.y == si && (jg + 1) < i);
        r += (v.z > si) || (v.z == si && (jg + 2) < i);
        r += (v.w > si) || (v.w == si && (jg + 3) < i);
    }
    atomicAdd(&rk[i], r);
}

__global__ __launch_bounds__(256) void k_perm(const int* rk, int* perm, int n, int k) {
    int i = blockIdx.x * blockDim.x + threadIdx.x;
    if (i >= n) return;
    int r = rk[i];
    if (r < k) perm[r] = i;
}

__global__ __launch_bounds__(256) void k_poolx(const float* x, const float* s, const int* perm, float* xp, int k) {
    int idx = blockIdx.x * blockDim.x + threadIdx.x;
    if (idx >= k * HID) return;
    int r = idx / HID, c = idx % HID;
    int pr = perm[r];
    xp[idx] = x[(size_t)pr * HID + c] * s[pr];
}

// ---------------- fp32 augment+pool path (level 2; split-K for occupancy) ----------------

template <class T>
__global__ __launch_bounds__(256) void k_gcols(const T* A, const int* perm, T* CG, int n, int kk) {
    size_t idx = (size_t)blockIdx.x * blockDim.x + threadIdx.x;
    if (idx >= (size_t)n * kk) return;
    int k = (int)(idx / kk), r2 = (int)(idx % kk);
    int pc = perm[r2];
    T v = A[(size_t)k * n + pc];
    if (k == pc) v = (T)(v + (T)1);
    CG[idx] = v;
}

// split-K partial GEMM: part[s][r][c] = sum_{k in chunk s} (A[perm[r]][k]+I) * CG[k][c]
__global__ __launch_bounds__(256) void k_gemm_pool_sk(const float* A, const int* perm, const float* CG,
                                                      float* part, int n, int kk, int chunk) {
    __shared__ float As[16][65];
    __shared__ float Bs[16][65];
    __shared__ int   pr[64];
    int r0 = blockIdx.y * 64, c0 = blockIdx.x * 64;
    int s  = blockIdx.z;
    int k_begin = s * chunk;
    int k_end   = min(k_begin + chunk, n);
    int tx = threadIdx.x % 16, ty = threadIdx.x / 16;

    for (int t = threadIdx.x; t < 64; t += 256) {
        int rg = r0 + t;
        pr[t] = (rg < kk) ? perm[rg] : -1;
    }
    __syncthreads();

    float acc[4][4] = {};
    int cB = threadIdx.x % 64, kB = threadIdx.x / 64;

    for (int k0 = k_begin; k0 < k_end; k0 += 16) {
        for (int pass = 0; pass < 4; pass++) {
            int rr = ty + pass * 16;
            int kk_ = k0 + tx;
            int prow = pr[rr];
            float v = 0.f;
            if (prow >= 0 && kk_ < k_end) {
                v = A[(size_t)prow * n + kk_];
                if (prow == kk_) v += 1.f;
            }
            As[tx][rr] = v;
        }
        for (int pass = 0; pass < 4; pass++) {
            int k = kB + 4 * pass;
            int cg = c0 + cB;
            float v = 0.f;
            if (cg < kk && (k0 + k) < k_end) v = CG[(size_t)(k0 + k) * kk + cg];
            Bs[k][cB] = v;
        }
        __syncthreads();
        for (int k = 0; k < 16; k++) {
            float a[4], b[4];
            #pragma unroll
            for (int i = 0; i < 4; i++) a[i] = As[k][ty * 4 + i];
            #pragma unroll
            for (int j = 0; j < 4; j++) b[j] = Bs[k][tx * 4 + j];
            #pragma unroll
            for (int i = 0; i < 4; i++)
                #pragma unroll
                for (int j = 0; j < 4; j++) acc[i][j] += a[i] * b[j];
        }
        __syncthreads();
    }
    for (int i = 0; i < 4; i++) {
        int rg = r0 + ty * 4 + i;
        if (rg >= kk) continue;
        for (int j = 0; j < 4; j++) {
            int cg = c0 + tx * 4 + j;
            if (cg >= kk) continue;
            part[((size_t)s * kk + rg) * kk + cg] = acc[i][j];
        }
    }
}

// reduce split-K partials, zero diagonal
__global__ __launch_bounds__(256) void k_gpfin(const float* __restrict__ part, int S, float* __restrict__ Ap, int kk) {
    int idx = blockIdx.x * blockDim.x + threadIdx.x;
    if (idx >= kk * kk) return;
    int rg = idx / kk, cg = idx % kk;
    float sum = 0.f;
    for (int s = 0; s < S; s++) sum += part[(size_t)s * kk * kk + idx];
    Ap[idx] = (rg == cg) ? 0.f : sum;
}

// ---------------- MFMA augment+pool path (levels 0,1; bf16-exact integer values) ----------------

// 32x32 f32 tiled transpose with guards
__global__ __launch_bounds__(256) void k_tr_f32(const float* A, float* AT, int n) {
    __shared__ float t[32][33];
    int bx = blockIdx.x * 32, by = blockIdx.y * 32;
    int tx = threadIdx.x % 32, ty = threadIdx.x / 32;
    for (int p = 0; p < 4; p++) {
        int r = by + ty + p * 8, c = bx + tx;
        t[ty + p * 8][tx] = (r < n && c < n) ? A[(size_t)r * n + c] : 0.f;
    }
    __syncthreads();
    for (int p = 0; p < 4; p++) {
        int r = bx + ty + p * 8, c = by + tx;
        if (r < n && c < n) AT[(size_t)r * n + c] = t[tx][ty + p * 8];
    }
}

// vectorized u8 -> bf16 row-gather of (A+I) by perm (n == Kpad == 4096)
__global__ __launch_bounds__(256) void k_prep8(const unsigned char* src, int n, int Kpad,
                                               const int* perm, int kk, unsigned short* dst) {
    int r = blockIdx.x;
    unsigned short* drow = dst + (size_t)r * Kpad;
    if (r >= kk) {
        ushort4 z = {0, 0, 0, 0};
        for (int k = threadIdx.x * 4; k < Kpad; k += 1024) *(ushort4*)&drow[k] = z;
        return;
    }
    int pr = perm[r];
    const unsigned char* srow = src + (size_t)pr * n;
    for (int k0 = threadIdx.x * 16; k0 < n; k0 += 4096) {
        uint4 w = *(const uint4*)&srow[k0];
        #pragma unroll
        for (int q = 0; q < 4; q++) {
            ushort4 o;
            #pragma unroll
            for (int j = 0; j < 4; j++) {
                unsigned b = (((const unsigned*)&w)[q] >> (8 * j)) & 0xffu;
                float v = (float)b + ((k0 + q * 4 + j == pr) ? 1.f : 0.f);
                ((unsigned short*)&o)[j] = (unsigned short)(__float_as_uint(v) >> 16);
            }
            *(ushort4*)&drow[k0 + q * 4] = o;
        }
    }
}

// f32 -> bf16 row-gather of (A+I) by perm, padded
__global__ __launch_bounds__(256) void k_prepf(const float* src, int n, int Kpad,
                                               const int* perm, int kk, unsigned short* dst) {
    int r = blockIdx.x;
    unsigned short* drow = dst + (size_t)r * Kpad;
    if (r >= kk) {
        for (int k = threadIdx.x; k < Kpad; k += 256) drow[k] = 0;
        return;
    }
    int pr = perm[r];
    const float* srow = src + (size_t)pr * n;
    for (int k = threadIdx.x; k < Kpad; k += 256) {
        float v = (k < n) ? srow[k] : 0.f;
        if (k == pr) v += 1.f;
        drow[k] = (unsigned short)(__float_as_uint(v) >> 16);
    }
}

// C[r][c] = sum_k Abf[r][k]*Bbf[c][k]; 128x128 tile, 4 waves, BK=64, bf16 MFMA, fp32 acc (exact ints)
__global__ __launch_bounds__(256) void k_mfma_pool(const unsigned short* Abf, const unsigned short* Bbf,
                                                   float* Ap, int Kpad, int kk) {
    __shared__ short As[128 * 64];
    __shared__ short Bs[128 * 64];
    int r0 = blockIdx.y * 128, c0 = blockIdx.x * 128;
    int tid = threadIdx.x;
    int l = tid & 63, w = tid >> 6;
    int wm = w >> 1, wn = w & 1;
    f32x4 acc[4][4] = {};

    for (int k0 = 0; k0 < Kpad; k0 += 64) {
        __syncthreads();
        #pragma unroll
        for (int p = 0; p < 4; p++) {
            int row = p * 32 + (tid >> 3);
            int ch  = tid & 7;
            int byte = row * 128 + ((ch * 16) ^ ((row & 7) << 4));
            bf16x8 va = *(const bf16x8*)&Abf[(size_t)(r0 + row) * Kpad + k0 + ch * 8];
            *(bf16x8*)((char*)As + byte) = va;
            bf16x8 vb = *(const bf16x8*)&Bbf[(size_t)(c0 + row) * Kpad + k0 + ch * 8];
            *(bf16x8*)((char*)Bs + byte) = vb;
        }
        __syncthreads();
        #pragma unroll
        for (int h = 0; h < 2; h++) {
            bf16x8 af[4], bfr[4];
            #pragma unroll
            for (int i = 0; i < 4; i++) {
                int row = wm * 64 + i * 16 + (l & 15);
                int byte = row * 128 + ((h * 64 + (l >> 4) * 16) ^ ((row & 7) << 4));
                af[i] = *(const bf16x8*)((const char*)As + byte);
            }
            #pragma unroll
            for (int j = 0; j < 4; j++) {
                int row = wn * 64 + j * 16 + (l & 15);
                int byte = row * 128 + ((h * 64 + (l >> 4) * 16) ^ ((row & 7) << 4));
                bfr[j] = *(const bf16x8*)((const char*)Bs + byte);
            }
            #pragma unroll
            for (int i = 0; i < 4; i++)
                #pragma unroll
                for (int j = 0; j < 4; j++)
                    acc[i][j] = __builtin_amdgcn_mfma_f32_16x16x32_bf16(af[i], bfr[j], acc[i][j], 0, 0, 0);
        }
    }
    #pragma unroll
    for (int i = 0; i < 4; i++) {
        #pragma unroll
        for (int j = 0; j < 4; j++) {
            int cg = c0 + wn * 64 + j * 16 + (l & 15);
            if (cg < kk) {
                #pragma unroll
                for (int q = 0; q < 4; q++) {
                    int rg = r0 + wm * 64 + i * 16 + (l >> 4) * 4 + q;
                    if (rg < kk) Ap[(size_t)rg * kk + cg] = (rg == cg) ? 0.f : acc[i][j][q];
                }
            }
        }
    }
}

// ---------------- up path + output ----------------

__global__ __launch_bounds__(256) void k_scadd(float* h, const float* xs, const int* perm, int k) {
    int idx = blockIdx.x * blockDim.x + threadIdx.x;
    if (idx >= k * HID) return;
    int r = idx / HID, c = idx % HID;
    h[(size_t)perm[r] * HID + c] += xs[idx];
}

__global__ __launch_bounds__(256) void k_logsm(const float* in, float* out, int n) {
    int i = blockIdx.x * blockDim.x + threadIdx.x;
    if (i >= n) return;
    const float* r = in + (size_t)i * NCLS;
    float m = -1e30f;
    for (int c = 0; c < NCLS; c++) m = fmaxf(m, r[c]);
    float sum = 0.f;
    for (int c = 0; c < NCLS; c++) sum += expf(r[c] - m);
    float ls = logf(sum);
    float* o = out + (size_t)i * NCLS;
    for (int c = 0; c < NCLS; c++) o[c] = r[c] - m - ls;
}

// ---------------- host ----------------

extern "C" void kernel_launch(void* const* d_in, const int* in_sizes, int n_in,
                              void* d_out, int out_size, void* d_ws, size_t ws_size,
                              hipStream_t stream) {
    const float* x  = (const float*)d_in[0];
    const int*   ei = (const int*)d_in[1];
    const float* W0 = (const float*)d_in[2];  const float* b0 = (const float*)d_in[3];
    const float* W1 = (const float*)d_in[4];  const float* b1 = (const float*)d_in[5];
    const float* W2 = (const float*)d_in[6];  const float* b2 = (const float*)d_in[7];
    const float* W3 = (const float*)d_in[8];  const float* b3 = (const float*)d_in[9];
    const float* U0 = (const float*)d_in[10]; const float* c0 = (const float*)d_in[11];
    const float* U1 = (const float*)d_in[12]; const float* c1 = (const float*)d_in[13];
    const float* U2 = (const float*)d_in[14]; const float* c2 = (const float*)d_in[15];
    const float* p0 = (const float*)d_in[16];
    const float* p1 = (const float*)d_in[17];
    const float* p2 = (const float*)d_in[18];
    float* out = (float*)d_out;

    char* w = (char*)d_ws;
    size_t off = 0;
    auto alloc = [&](size_t bytes) -> void* {
        void* p = w + off;
        off += (bytes + 255) / 256 * 256;
        return p;
    };
    unsigned char* A0u = (unsigned char*)alloc((size_t)N0 * N0);
    unsigned char* A0T = (unsigned char*)alloc((size_t)N0 * N0);
    float* A1  = (float*)alloc((size_t)KP1 * KP1 * 4);
    float* A1T = (float*)alloc((size_t)KP1 * KP1 * 4);
    float* A2  = (float*)alloc((size_t)KP2 * KP2 * 4);
    float* A3  = (float*)alloc((size_t)KP3 * KP3 * 4);
    float* CG  = (float*)alloc((size_t)KP2 * KP3 * 4);
    unsigned short* Abf = (unsigned short*)alloc((size_t)2048 * 4096 * 2);
    unsigned short* Bbf = (unsigned short*)alloc((size_t)2048 * 4096 * 2);
    float* part = (float*)alloc((size_t)4 * N0 * HID * 4);
    float* x0  = (float*)alloc((size_t)N0 * HID * 4);
    float* x1  = (float*)alloc((size_t)KP1 * HID * 4);
    float* x2  = (float*)alloc((size_t)KP2 * HID * 4);
    float* x3  = (float*)alloc((size_t)KP3 * HID * 4);
    float* xp  = (float*)alloc((size_t)KP1 * HID * 4);
    float* ua  = (float*)alloc((size_t)KP2 * HID * 4);
    float* ub  = (float*)alloc((size_t)KP1 * HID * 4);
    float* hb  = (float*)alloc((size_t)N0 * HID * 4);
    float* xw  = (float*)alloc((size_t)N0 * HID * 4);
    float* yb  = (float*)alloc((size_t)N0 * HID * 4);
    float* dv0 = (float*)alloc((size_t)N0 * 4);
    float* dv1 = (float*)alloc((size_t)KP1 * 4);
    float* dv2 = (float*)alloc((size_t)KP2 * 4);
    float* dv3 = (float*)alloc((size_t)KP3 * 4);
    float* sc  = (float*)alloc((size_t)N0 * 4);
    float* o16 = (float*)alloc((size_t)N0 * NCLS * 4);
    int*   rk  = (int*)alloc((size_t)N0 * 4);
    int*   pm0 = (int*)alloc((size_t)KP1 * 4);
    int*   pm1 = (int*)alloc((size_t)KP2 * 4);
    int*   pm2 = (int*)alloc((size_t)KP3 * 4);
    (void)ws_size; (void)in_sizes; (void)n_in; (void)out_size;

    auto gcn_u8_32 = [&](const unsigned char* A, int n, const float* xin, int K, const float* W,
                         const float* bias, const float* dvv, int relu, float* outv, int S, int chunk) {
        k_xw<<<n, 256, 0, stream>>>(xin, W, xw, K, 32);
        k_scaley<<<(n * 32 + 255) / 256, 256, 0, stream>>>(xw, dvv, yb, n * 32, 32);
        dim3 g((n + 63) / 64, S);
        k_agg<unsigned char, 32><<<g, 256, 0, stream>>>(A, yb, part, n, n, chunk);
        k_aggfin<32><<<(n * 32 + 255) / 256, 256, 0, stream>>>(part, S, yb, dvv, bias, outv, n, relu);
    };
    auto gcn_u8_16 = [&](const unsigned char* A, int n, const float* xin, int K, const float* W,
                         const float* bias, const float* dvv, int relu, float* outv, int S, int chunk) {
        k_xw<<<n, 256, 0, stream>>>(xin, W, xw, K, 16);
        k_scaley<<<(n * 16 + 255) / 256, 256, 0, stream>>>(xw, dvv, yb, n * 16, 16);
        dim3 g((n + 63) / 64, S);
        k_agg<unsigned char, 16><<<g, 256, 0, stream>>>(A, yb, part, n, n, chunk);
        k_aggfin<16><<<(n * 16 + 255) / 256, 256, 0, stream>>>(part, S, yb, dvv, bias, outv, n, relu);
    };
    auto gcn_f = [&](const float* A, int n, const float* xin, int K, const float* W,
                     const float* bias, const float* dvv, int relu, float* outv, int S, int chunk) {
        k_xw<<<n, 256, 0, stream>>>(xin, W, xw, K, 32);
        k_scaley<<<(n * 32 + 255) / 256, 256, 0, stream>>>(xw, dvv, yb, n * 32, 32);
        dim3 g((n + 63) / 64, S);
        k_agg<float, 32><<<g, 256, 0, stream>>>(A, yb, part, n, n, chunk);
        k_aggfin<32><<<(n * 32 + 255) / 256, 256, 0, stream>>>(part, S, yb, dvv, bias, outv, n, relu);
    };
    auto pool = [&](const float* xin, const float* p, int n, int k, int* perm, float* xpo) {
        k_score<<<(n + 255) / 256, 256, 0, stream>>>(xin, p, sc, n);
        k_fill0_u32<<<16, 256, 0, stream>>>((unsigned*)rk, (size_t)n);
        dim3 gr((n + 255) / 256, (n + RCH - 1) / RCH);
        k_rank2<<<gr, 256, 0, stream>>>(sc, rk, n);
        k_perm<<<(n + 255) / 256, 256, 0, stream>>>(rk, perm, n, k);
        k_poolx<<<(k * HID + 255) / 256, 256, 0, stream>>>(xin, sc, perm, xpo, k);
    };

    // build dense adjacency + transpose
    k_fill0_u32<<<2048, 256, 0, stream>>>((unsigned*)A0u, (size_t)N0 * N0 / 4);
    k_fill0_u32<<<2048, 256, 0, stream>>>((unsigned*)A0T, (size_t)N0 * N0 / 4);
    k_scatter2<<<(NE + 255) / 256, 256, 0, stream>>>(ei, (unsigned*)A0u, (unsigned*)A0T);

    // degrees (once per level)
    k_deg8<<<N0, 256, 0, stream>>>(A0u, N0, dv0);

    // ---- down path ----
    gcn_u8_32(A0u, N0, x, FIN, W0, b0, dv0, 1, x0, 4, 1024);
    pool(x0, p0, N0, KP1, pm0, xp);

    k_prep8<<<2048, 256, 0, stream>>>(A0u, N0, 4096, pm0, KP1, Abf);
    k_prep8<<<2048, 256, 0, stream>>>(A0T, N0, 4096, pm0, KP1, Bbf);
    k_mfma_pool<<<dim3(16, 16), 256, 0, stream>>>(Abf, Bbf, A1, 4096, KP1);

    k_degf<<<KP1, 256, 0, stream>>>(A1, KP1, dv1);
    gcn_f(A1, KP1, xp, HID, W1, b1, dv1, 1, x1, 8, 256);
    k_tr_f32<<<dim3(63, 63), 256, 0, stream>>>(A1, A1T, KP1);
    pool(x1, p1, KP1, KP2, pm1, xp);

    k_prepf<<<1024, 256, 0, stream>>>(A1, KP1, 2048, pm1, KP2, Abf);
    k_prepf<<<1024, 256, 0, stream>>>(A1T, KP1, 2048, pm1, KP2, Bbf);
    k_mfma_pool<<<dim3(8, 8), 256, 0, stream>>>(Abf, Bbf, A2, 2048, KP2);

    k_degf<<<KP2, 256, 0, stream>>>(A2, KP2, dv2);
    gcn_f(A2, KP2, xp, HID, W2, b2, dv2, 1, x2, 16, 64);
    pool(x2, p2, KP2, KP3, pm2, xp);

    // L2 augment+pool: exact fp32, split-K (S=16) for occupancy; partials reuse Abf (idle here)
    {
        size_t tot = (size_t)KP2 * KP3;
        k_gcols<float><<<(int)((tot + 255) / 256), 256, 0, stream>>>(A2, pm2, CG, KP2, KP3);
        float* pbuf = (float*)Abf;   // 16 MB needed (16*500*500*4B), Abf has 16.8 MB
        k_gemm_pool_sk<<<dim3(8, 8, 16), 256, 0, stream>>>(A2, pm2, CG, pbuf, KP2, KP3, 64);
        k_gpfin<<<(KP3 * KP3 + 255) / 256, 256, 0, stream>>>(pbuf, 16, A3, KP3);
    }
    k_degf<<<KP3, 256, 0, stream>>>(A3, KP3, dv3);
    gcn_f(A3, KP3, xp, HID, W3, b3, dv3, 1, x3, 8, 64);

    // ---- up path ----
    k_copy<<<(KP2 * HID + 255) / 256, 256, 0, stream>>>(hb, x2, KP2 * HID);
    k_scadd<<<(KP3 * HID + 255) / 256, 256, 0, stream>>>(hb, x3, pm2, KP3);
    gcn_f(A2, KP2, hb, HID, U0, c0, dv2, 1, ua, 16, 64);

    k_copy<<<(KP1 * HID + 255) / 256, 256, 0, stream>>>(hb, x1, KP1 * HID);
    k_scadd<<<(KP2 * HID + 255) / 256, 256, 0, stream>>>(hb, ua, pm1, KP2);
    gcn_f(A1, KP1, hb, HID, U1, c1, dv1, 1, ub, 8, 256);

    k_copy<<<(N0 * HID + 255) / 256, 256, 0, stream>>>(hb, x0, N0 * HID);
    k_scadd<<<(KP1 * HID + 255) / 256, 256, 0, stream>>>(hb, ub, pm0, KP1);
    gcn_u8_16(A0u, N0, hb, HID, U2, c2, dv0, 0, o16, 4, 1024);

    k_logsm<<<(N0 + 255) / 256, 256, 0, stream>>>(o16, out, N0);
}

// Round 8
// 542.257 us; speedup vs baseline: 4.5956x; 1.1202x over previous
//
#include <hip/hip_runtime.h>
#include <math.h>
#include <stddef.h>

#define N0   4096
#define NE   131072
#define FIN  1433
#define HID  32
#define NCLS 16
#define KP1  2000
#define KP2  1000
#define KP3  500
#define RCH  512

typedef __attribute__((ext_vector_type(8))) short bf16x8;
typedef __attribute__((ext_vector_type(4))) float f32x4;

// ---------------- basic utils ----------------

__global__ __launch_bounds__(256) void k_fill0_u32(unsigned* p, size_t n) {
    size_t i = (size_t)blockIdx.x * blockDim.x + threadIdx.x;
    size_t st = (size_t)gridDim.x * blockDim.x;
    for (; i < n; i += st) p[i] = 0u;
}

__global__ __launch_bounds__(256) void k_copy(float* dst, const float* src, int n) {
    int i = blockIdx.x * blockDim.x + threadIdx.x;
    if (i < n) dst[i] = src[i];
}

// scatter into A0 and A0^T (packed u8 byte-lane atomics; exact small counts)
__global__ __launch_bounds__(256) void k_scatter2(const int* ei, unsigned* A0w, unsigned* A0Tw) {
    int e = blockIdx.x * blockDim.x + threadIdx.x;
    if (e >= NE) return;
    int r = ei[e], c = ei[NE + e];
    if (r == c) return;
    size_t idx = (size_t)r * N0 + c;
    atomicAdd(&A0w[idx >> 2], 1u << (8 * (idx & 3)));
    size_t idt = (size_t)c * N0 + r;
    atomicAdd(&A0Tw[idt >> 2], 1u << (8 * (idt & 3)));
}

// vectorized deg for u8 adjacency (n multiple of 16): dv[i]=1/sqrt(rowsum+2)
__global__ __launch_bounds__(256) void k_deg8(const unsigned char* A, int n, float* dv) {
    int i = blockIdx.x;
    const unsigned char* row = A + (size_t)i * n;
    unsigned accu = 0;
    for (int j = threadIdx.x * 16; j < n; j += 256 * 16) {
        uint4 w = *(const uint4*)&row[j];
        #pragma unroll
        for (int q = 0; q < 4; q++) {
            unsigned v = ((const unsigned*)&w)[q];
            accu += (v & 0xff) + ((v >> 8) & 0xff) + ((v >> 16) & 0xff) + (v >> 24);
        }
    }
    __shared__ float red[256];
    red[threadIdx.x] = (float)accu; __syncthreads();
    for (int off = 128; off > 0; off >>= 1) {
        if (threadIdx.x < off) red[threadIdx.x] += red[threadIdx.x + off];
        __syncthreads();
    }
    if (threadIdx.x == 0) dv[i] = (float)(1.0 / sqrt((double)red[0] + 2.0));
}

// vectorized deg for f32 adjacency (n multiple of 4); entries are exact integers
__global__ __launch_bounds__(256) void k_degf(const float* A, int n, float* dv) {
    int i = blockIdx.x;
    const float* row = A + (size_t)i * n;
    float acc = 0.f;
    for (int j = threadIdx.x * 4; j < n; j += 256 * 4) {
        float4 w = *(const float4*)&row[j];
        acc += w.x + w.y + w.z + w.w;
    }
    __shared__ float red[256];
    red[threadIdx.x] = acc; __syncthreads();
    for (int off = 128; off > 0; off >>= 1) {
        if (threadIdx.x < off) red[threadIdx.x] += red[threadIdx.x + off];
        __syncthreads();
    }
    if (threadIdx.x == 0) dv[i] = (float)(1.0 / sqrt((double)red[0] + 2.0));
}

// tiled XW GEMM: XW[i][c] = sum_k X[i][k]*W[k][c]; BR rows/block, BK=64 K-chunk, LDS staged
template <int NC>
__global__ __launch_bounds__(256) void k_xw2(const float* __restrict__ X, const float* __restrict__ W,
                                             float* __restrict__ XW, int M, int K) {
    constexpr int BR = 256 / NC;         // 8 rows (NC=32) or 16 rows (NC=16)
    constexpr int BK = 64;
    constexpr int XEL = BR * BK / 256;   // 2 or 4 X elements per thread
    constexpr int WEL = BK * NC / 256;   // 8 or 4 W elements per thread
    __shared__ float Xs[BR][BK + 4];
    __shared__ float Ws[BK][NC];
    int r0 = blockIdx.x * BR;
    int tid = threadIdx.x;
    int c = tid % NC, r = tid / NC;
    int xli = tid * XEL, xr = xli / BK, xc = xli % BK;
    int wli = tid * WEL, wk = wli / NC, wc = wli % NC;
    int grow = r0 + xr;
    float acc = 0.f;

    for (int k0 = 0; k0 < K; k0 += BK) {
        __syncthreads();
        if (k0 + BK <= K && grow < M) {
            #pragma unroll
            for (int e = 0; e < XEL; e++) Xs[xr][xc + e] = X[(size_t)grow * K + k0 + xc + e];
        } else {
            #pragma unroll
            for (int e = 0; e < XEL; e++) {
                int kk = k0 + xc + e;
                Xs[xr][xc + e] = (grow < M && kk < K) ? X[(size_t)grow * K + kk] : 0.f;
            }
        }
        if (k0 + wk < K) {
            #pragma unroll
            for (int e = 0; e < WEL; e += 4)
                *(float4*)&Ws[wk][wc + e] = *(const float4*)&W[(size_t)(k0 + wk) * NC + wc + e];
        } else {
            #pragma unroll
            for (int e = 0; e < WEL; e++) Ws[wk][wc + e] = 0.f;
        }
        __syncthreads();
        #pragma unroll 8
        for (int k = 0; k < BK; k++) acc += Xs[r][k] * Ws[k][c];
    }
    if (r0 + r < M) XW[(size_t)(r0 + r) * NC + c] = acc;
}

__global__ __launch_bounds__(256) void k_scaley(const float* xw, const float* dv, float* y, int tot, int NC) {
    int i = blockIdx.x * blockDim.x + threadIdx.x;
    if (i < tot) y[i] = dv[i / NC] * xw[i];
}

// ---------------- tiled split-K aggregation: part[s][i][c] = sum_{k in chunk s} A[i][k]*y[k][c] ----------------

template <class T, int NC>
__global__ __launch_bounds__(256) void k_agg(const T* __restrict__ A, const float* __restrict__ y,
                                             float* __restrict__ part, int n, int M, int chunk) {
    constexpr int G   = 256 / NC;
    constexpr int RPT = 64 / G;
    __shared__ float At[64][72];
    __shared__ float ys[64][NC];
    int r0 = blockIdx.x * 64;
    int s  = blockIdx.y;
    int k_begin = s * chunk;
    int k_end   = min(k_begin + chunk, n);
    int tid = threadIdx.x;
    int c = tid % NC, g = tid / NC;
    int r = tid & 63, kq = tid >> 6;
    bool row_ok = (r0 + r) < M;
    float acc[RPT] = {};

    for (int k0 = k_begin; k0 < k_end; k0 += 64) {
        __syncthreads();
        if constexpr (sizeof(T) == 1) {
            uint4 w = {0u, 0u, 0u, 0u};
            if (row_ok) w = *(const uint4*)&A[(size_t)(r0 + r) * n + k0 + kq * 16];
            #pragma unroll
            for (int j = 0; j < 16; j++) {
                int kl = kq * 16 + j;
                unsigned b = (((const unsigned*)&w)[j >> 2] >> (8 * (j & 3))) & 0xffu;
                At[kl][r] = (k0 + kl < k_end) ? (float)b : 0.f;
            }
        } else {
            #pragma unroll
            for (int q = 0; q < 4; q++) {
                int kl = kq * 16 + q * 4;
                float4 w = {0.f, 0.f, 0.f, 0.f};
                if (row_ok) w = *(const float4*)&A[(size_t)(r0 + r) * n + k0 + kl];
                At[kl + 0][r] = (k0 + kl + 0 < k_end) ? w.x : 0.f;
                At[kl + 1][r] = (k0 + kl + 1 < k_end) ? w.y : 0.f;
                At[kl + 2][r] = (k0 + kl + 2 < k_end) ? w.z : 0.f;
                At[kl + 3][r] = (k0 + kl + 3 < k_end) ? w.w : 0.f;
            }
        }
        constexpr int NF4 = 64 * NC / 4;
        #pragma unroll
        for (int f = 0; f < NF4 / 256; f++) {
            int fi = tid + f * 256;
            int k = fi / (NC / 4), cb = fi % (NC / 4);
            float4 w = *(const float4*)&y[(size_t)(k0 + k) * NC + cb * 4];
            *(float4*)&ys[k][cb * 4] = w;
        }
        __syncthreads();
        for (int k = 0; k < 64; k++) {
            float yv = ys[k][c];
            #pragma unroll
            for (int i = 0; i < RPT; i += 4) {
                float4 a = *(const float4*)&At[k][g * RPT + i];
                acc[i + 0] += a.x * yv;
                acc[i + 1] += a.y * yv;
                acc[i + 2] += a.z * yv;
                acc[i + 3] += a.w * yv;
            }
        }
    }
    #pragma unroll
    for (int i = 0; i < RPT; i++) {
        int row = r0 + g * RPT + i;
        if (row < M) part[((size_t)s * M + row) * NC + c] = acc[i];
    }
}

template <int NC>
__global__ __launch_bounds__(256) void k_aggfin(const float* __restrict__ part, int S,
                                                const float* __restrict__ y, const float* __restrict__ dvv,
                                                const float* __restrict__ bias, float* __restrict__ out,
                                                int M, int relu) {
    int idx = blockIdx.x * blockDim.x + threadIdx.x;
    if (idx >= M * NC) return;
    int i = idx / NC, c = idx % NC;
    float sum = 0.f;
    for (int s = 0; s < S; s++) sum += part[(size_t)s * M * NC + idx];
    float di = dvv[i];
    float v = di * sum + 2.f * di * y[idx] + bias[c];
    if (relu) v = fmaxf(v, 0.f);
    out[idx] = v;
}

// ---------------- top-k pooling ----------------

__global__ __launch_bounds__(256) void k_score(const float* x, const float* p, float* s, int n) {
    int i = blockIdx.x * blockDim.x + threadIdx.x;
    if (i >= n) return;
    float nrm = 0.f;
    for (int c = 0; c < HID; c++) nrm += p[c] * p[c];
    nrm = sqrtf(nrm);
    const float* xr = x + (size_t)i * HID;
    float d = 0.f;
    for (int c = 0; c < HID; c++) d += xr[c] * p[c];
    s[i] = tanhf(d / nrm);
}

// split-j LDS-staged rank (rk zeroed first; integer atomics exact)
__global__ __launch_bounds__(256) void k_rank2(const float* __restrict__ s, int* __restrict__ rk, int n) {
    __shared__ float sj[RCH];
    int i  = blockIdx.x * 256 + threadIdx.x;
    int jb = blockIdx.y * RCH;
    int len = min(jb + RCH, n) - jb;
    for (int j = threadIdx.x * 4; j < len; j += 1024)
        *(float4*)&sj[j] = *(const float4*)&s[jb + j];
    __syncthreads();
    if (i >= n) return;
    float si = s[i];
    int r = 0;
    for (int j = 0; j < len; j += 4) {
        float4 v = *(const float4*)&sj[j];
        int jg = jb + j;
        r += (v.x > si) || (v.x == si && (jg + 0) < i);
        r += (v.y > si) || (v.y == si && (jg + 1) < i);
        r += (v.z > si) || (v.z == si && (jg + 2) < i);
        r += (v.w > si) || (v.w == si && (jg + 3) < i);
    }
    atomicAdd(&rk[i], r);
}

__global__ __launch_bounds__(256) void k_perm(const int* rk, int* perm, int n, int k) {
    int i = blockIdx.x * blockDim.x + threadIdx.x;
    if (i >= n) return;
    int r = rk[i];
    if (r < k) perm[r] = i;
}

__global__ __launch_bounds__(256) void k_poolx(const float* x, const float* s, const int* perm, float* xp, int k) {
    int idx = blockIdx.x * blockDim.x + threadIdx.x;
    if (idx >= k * HID) return;
    int r = idx / HID, c = idx % HID;
    int pr = perm[r];
    xp[idx] = x[(size_t)pr * HID + c] * s[pr];
}

// ---------------- fp32 augment+pool path (level 2; split-K for occupancy) ----------------

template <class T>
__global__ __launch_bounds__(256) void k_gcols(const T* A, const int* perm, T* CG, int n, int kk) {
    size_t idx = (size_t)blockIdx.x * blockDim.x + threadIdx.x;
    if (idx >= (size_t)n * kk) return;
    int k = (int)(idx / kk), r2 = (int)(idx % kk);
    int pc = perm[r2];
    T v = A[(size_t)k * n + pc];
    if (k == pc) v = (T)(v + (T)1);
    CG[idx] = v;
}

// split-K partial GEMM: part[s][r][c] = sum_{k in chunk s} (A[perm[r]][k]+I) * CG[k][c]
__global__ __launch_bounds__(256) void k_gemm_pool_sk(const float* A, const int* perm, const float* CG,
                                                      float* part, int n, int kk, int chunk) {
    __shared__ float As[16][65];
    __shared__ float Bs[16][65];
    __shared__ int   pr[64];
    int r0 = blockIdx.y * 64, c0 = blockIdx.x * 64;
    int s  = blockIdx.z;
    int k_begin = s * chunk;
    int k_end   = min(k_begin + chunk, n);
    int tx = threadIdx.x % 16, ty = threadIdx.x / 16;

    for (int t = threadIdx.x; t < 64; t += 256) {
        int rg = r0 + t;
        pr[t] = (rg < kk) ? perm[rg] : -1;
    }
    __syncthreads();

    float acc[4][4] = {};
    int cB = threadIdx.x % 64, kB = threadIdx.x / 64;

    for (int k0 = k_begin; k0 < k_end; k0 += 16) {
        for (int pass = 0; pass < 4; pass++) {
            int rr = ty + pass * 16;
            int kk_ = k0 + tx;
            int prow = pr[rr];
            float v = 0.f;
            if (prow >= 0 && kk_ < k_end) {
                v = A[(size_t)prow * n + kk_];
                if (prow == kk_) v += 1.f;
            }
            As[tx][rr] = v;
        }
        for (int pass = 0; pass < 4; pass++) {
            int k = kB + 4 * pass;
            int cg = c0 + cB;
            float v = 0.f;
            if (cg < kk && (k0 + k) < k_end) v = CG[(size_t)(k0 + k) * kk + cg];
            Bs[k][cB] = v;
        }
        __syncthreads();
        for (int k = 0; k < 16; k++) {
            float a[4], b[4];
            #pragma unroll
            for (int i = 0; i < 4; i++) a[i] = As[k][ty * 4 + i];
            #pragma unroll
            for (int j = 0; j < 4; j++) b[j] = Bs[k][tx * 4 + j];
            #pragma unroll
            for (int i = 0; i < 4; i++)
                #pragma unroll
                for (int j = 0; j < 4; j++) acc[i][j] += a[i] * b[j];
        }
        __syncthreads();
    }
    for (int i = 0; i < 4; i++) {
        int rg = r0 + ty * 4 + i;
        if (rg >= kk) continue;
        for (int j = 0; j < 4; j++) {
            int cg = c0 + tx * 4 + j;
            if (cg >= kk) continue;
            part[((size_t)s * kk + rg) * kk + cg] = acc[i][j];
        }
    }
}

// reduce split-K partials, zero diagonal
__global__ __launch_bounds__(256) void k_gpfin(const float* __restrict__ part, int S, float* __restrict__ Ap, int kk) {
    int idx = blockIdx.x * blockDim.x + threadIdx.x;
    if (idx >= kk * kk) return;
    int rg = idx / kk, cg = idx % kk;
    float sum = 0.f;
    for (int s = 0; s < S; s++) sum += part[(size_t)s * kk * kk + idx];
    Ap[idx] = (rg == cg) ? 0.f : sum;
}

// ---------------- MFMA augment+pool path (levels 0,1; bf16-exact integer values) ----------------

// 32x32 f32 tiled transpose with guards
__global__ __launch_bounds__(256) void k_tr_f32(const float* A, float* AT, int n) {
    __shared__ float t[32][33];
    int bx = blockIdx.x * 32, by = blockIdx.y * 32;
    int tx = threadIdx.x % 32, ty = threadIdx.x / 32;
    for (int p = 0; p < 4; p++) {
        int r = by + ty + p * 8, c = bx + tx;
        t[ty + p * 8][tx] = (r < n && c < n) ? A[(size_t)r * n + c] : 0.f;
    }
    __syncthreads();
    for (int p = 0; p < 4; p++) {
        int r = bx + ty + p * 8, c = by + tx;
        if (r < n && c < n) AT[(size_t)r * n + c] = t[tx][ty + p * 8];
    }
}

// vectorized u8 -> bf16 row-gather of (A+I) by perm (n == Kpad == 4096)
__global__ __launch_bounds__(256) void k_prep8(const unsigned char* src, int n, int Kpad,
                                               const int* perm, int kk, unsigned short* dst) {
    int r = blockIdx.x;
    unsigned short* drow = dst + (size_t)r * Kpad;
    if (r >= kk) {
        ushort4 z = {0, 0, 0, 0};
        for (int k = threadIdx.x * 4; k < Kpad; k += 1024) *(ushort4*)&drow[k] = z;
        return;
    }
    int pr = perm[r];
    const unsigned char* srow = src + (size_t)pr * n;
    for (int k0 = threadIdx.x * 16; k0 < n; k0 += 4096) {
        uint4 w = *(const uint4*)&srow[k0];
        #pragma unroll
        for (int q = 0; q < 4; q++) {
            ushort4 o;
            #pragma unroll
            for (int j = 0; j < 4; j++) {
                unsigned b = (((const unsigned*)&w)[q] >> (8 * j)) & 0xffu;
                float v = (float)b + ((k0 + q * 4 + j == pr) ? 1.f : 0.f);
                ((unsigned short*)&o)[j] = (unsigned short)(__float_as_uint(v) >> 16);
            }
            *(ushort4*)&drow[k0 + q * 4] = o;
        }
    }
}

// f32 -> bf16 row-gather of (A+I) by perm, padded
__global__ __launch_bounds__(256) void k_prepf(const float* src, int n, int Kpad,
                                               const int* perm, int kk, unsigned short* dst) {
    int r = blockIdx.x;
    unsigned short* drow = dst + (size_t)r * Kpad;
    if (r >= kk) {
        for (int k = threadIdx.x; k < Kpad; k += 256) drow[k] = 0;
        return;
    }
    int pr = perm[r];
    const float* srow = src + (size_t)pr * n;
    for (int k = threadIdx.x; k < Kpad; k += 256) {
        float v = (k < n) ? srow[k] : 0.f;
        if (k == pr) v += 1.f;
        drow[k] = (unsigned short)(__float_as_uint(v) >> 16);
    }
}

// C[r][c] = sum_k Abf[r][k]*Bbf[c][k]; 128x128 tile, 4 waves, BK=64, bf16 MFMA, fp32 acc (exact ints)
__global__ __launch_bounds__(256) void k_mfma_pool(const unsigned short* Abf, const unsigned short* Bbf,
                                                   float* Ap, int Kpad, int kk) {
    __shared__ short As[128 * 64];
    __shared__ short Bs[128 * 64];
    int r0 = blockIdx.y * 128, c0 = blockIdx.x * 128;
    int tid = threadIdx.x;
    int l = tid & 63, w = tid >> 6;
    int wm = w >> 1, wn = w & 1;
    f32x4 acc[4][4] = {};

    for (int k0 = 0; k0 < Kpad; k0 += 64) {
        __syncthreads();
        #pragma unroll
        for (int p = 0; p < 4; p++) {
            int row = p * 32 + (tid >> 3);
            int ch  = tid & 7;
            int byte = row * 128 + ((ch * 16) ^ ((row & 7) << 4));
            bf16x8 va = *(const bf16x8*)&Abf[(size_t)(r0 + row) * Kpad + k0 + ch * 8];
            *(bf16x8*)((char*)As + byte) = va;
            bf16x8 vb = *(const bf16x8*)&Bbf[(size_t)(c0 + row) * Kpad + k0 + ch * 8];
            *(bf16x8*)((char*)Bs + byte) = vb;
        }
        __syncthreads();
        #pragma unroll
        for (int h = 0; h < 2; h++) {
            bf16x8 af[4], bfr[4];
            #pragma unroll
            for (int i = 0; i < 4; i++) {
                int row = wm * 64 + i * 16 + (l & 15);
                int byte = row * 128 + ((h * 64 + (l >> 4) * 16) ^ ((row & 7) << 4));
                af[i] = *(const bf16x8*)((const char*)As + byte);
            }
            #pragma unroll
            for (int j = 0; j < 4; j++) {
                int row = wn * 64 + j * 16 + (l & 15);
                int byte = row * 128 + ((h * 64 + (l >> 4) * 16) ^ ((row & 7) << 4));
                bfr[j] = *(const bf16x8*)((const char*)Bs + byte);
            }
            #pragma unroll
            for (int i = 0; i < 4; i++)
                #pragma unroll
                for (int j = 0; j < 4; j++)
                    acc[i][j] = __builtin_amdgcn_mfma_f32_16x16x32_bf16(af[i], bfr[j], acc[i][j], 0, 0, 0);
        }
    }
    #pragma unroll
    for (int i = 0; i < 4; i++) {
        #pragma unroll
        for (int j = 0; j < 4; j++) {
            int cg = c0 + wn * 64 + j * 16 + (l & 15);
            if (cg < kk) {
                #pragma unroll
                for (int q = 0; q < 4; q++) {
                    int rg = r0 + wm * 64 + i * 16 + (l >> 4) * 4 + q;
                    if (rg < kk) Ap[(size_t)rg * kk + cg] = (rg == cg) ? 0.f : acc[i][j][q];
                }
            }
        }
    }
}

// ---------------- up path + output ----------------

__global__ __launch_bounds__(256) void k_scadd(float* h, const float* xs, const int* perm, int k) {
    int idx = blockIdx.x * blockDim.x + threadIdx.x;
    if (idx >= k * HID) return;
    int r = idx / HID, c = idx % HID;
    h[(size_t)perm[r] * HID + c] += xs[idx];
}

__global__ __launch_bounds__(256) void k_logsm(const float* in, float* out, int n) {
    int i = blockIdx.x * blockDim.x + threadIdx.x;
    if (i >= n) return;
    const float* r = in + (size_t)i * NCLS;
    float m = -1e30f;
    for (int c = 0; c < NCLS; c++) m = fmaxf(m, r[c]);
    float sum = 0.f;
    for (int c = 0; c < NCLS; c++) sum += expf(r[c] - m);
    float ls = logf(sum);
    float* o = out + (size_t)i * NCLS;
    for (int c = 0; c < NCLS; c++) o[c] = r[c] - m - ls;
}

// ---------------- host ----------------

extern "C" void kernel_launch(void* const* d_in, const int* in_sizes, int n_in,
                              void* d_out, int out_size, void* d_ws, size_t ws_size,
                              hipStream_t stream) {
    const float* x  = (const float*)d_in[0];
    const int*   ei = (const int*)d_in[1];
    const float* W0 = (const float*)d_in[2];  const float* b0 = (const float*)d_in[3];
    const float* W1 = (const float*)d_in[4];  const float* b1 = (const float*)d_in[5];
    const float* W2 = (const float*)d_in[6];  const float* b2 = (const float*)d_in[7];
    const float* W3 = (const float*)d_in[8];  const float* b3 = (const float*)d_in[9];
    const float* U0 = (const float*)d_in[10]; const float* c0 = (const float*)d_in[11];
    const float* U1 = (const float*)d_in[12]; const float* c1 = (const float*)d_in[13];
    const float* U2 = (const float*)d_in[14]; const float* c2 = (const float*)d_in[15];
    const float* p0 = (const float*)d_in[16];
    const float* p1 = (const float*)d_in[17];
    const float* p2 = (const float*)d_in[18];
    float* out = (float*)d_out;

    char* w = (char*)d_ws;
    size_t off = 0;
    auto alloc = [&](size_t bytes) -> void* {
        void* p = w + off;
        off += (bytes + 255) / 256 * 256;
        return p;
    };
    unsigned char* A0u = (unsigned char*)alloc((size_t)N0 * N0);
    unsigned char* A0T = (unsigned char*)alloc((size_t)N0 * N0);
    float* A1  = (float*)alloc((size_t)KP1 * KP1 * 4);
    float* A1T = (float*)alloc((size_t)KP1 * KP1 * 4);
    float* A2  = (float*)alloc((size_t)KP2 * KP2 * 4);
    float* A3  = (float*)alloc((size_t)KP3 * KP3 * 4);
    float* CG  = (float*)alloc((size_t)KP2 * KP3 * 4);
    unsigned short* Abf = (unsigned short*)alloc((size_t)2048 * 4096 * 2);
    unsigned short* Bbf = (unsigned short*)alloc((size_t)2048 * 4096 * 2);
    float* part = (float*)alloc((size_t)4 * N0 * HID * 4);
    float* x0  = (float*)alloc((size_t)N0 * HID * 4);
    float* x1  = (float*)alloc((size_t)KP1 * HID * 4);
    float* x2  = (float*)alloc((size_t)KP2 * HID * 4);
    float* x3  = (float*)alloc((size_t)KP3 * HID * 4);
    float* xp  = (float*)alloc((size_t)KP1 * HID * 4);
    float* ua  = (float*)alloc((size_t)KP2 * HID * 4);
    float* ub  = (float*)alloc((size_t)KP1 * HID * 4);
    float* hb  = (float*)alloc((size_t)N0 * HID * 4);
    float* xw  = (float*)alloc((size_t)N0 * HID * 4);
    float* yb  = (float*)alloc((size_t)N0 * HID * 4);
    float* dv0 = (float*)alloc((size_t)N0 * 4);
    float* dv1 = (float*)alloc((size_t)KP1 * 4);
    float* dv2 = (float*)alloc((size_t)KP2 * 4);
    float* dv3 = (float*)alloc((size_t)KP3 * 4);
    float* sc  = (float*)alloc((size_t)N0 * 4);
    float* o16 = (float*)alloc((size_t)N0 * NCLS * 4);
    int*   rk  = (int*)alloc((size_t)N0 * 4);
    int*   pm0 = (int*)alloc((size_t)KP1 * 4);
    int*   pm1 = (int*)alloc((size_t)KP2 * 4);
    int*   pm2 = (int*)alloc((size_t)KP3 * 4);
    (void)ws_size; (void)in_sizes; (void)n_in; (void)out_size;

    auto gcn_u8_32 = [&](const unsigned char* A, int n, const float* xin, int K, const float* W,
                         const float* bias, const float* dvv, int relu, float* outv, int S, int chunk) {
        k_xw2<32><<<(n + 7) / 8, 256, 0, stream>>>(xin, W, xw, n, K);
        k_scaley<<<(n * 32 + 255) / 256, 256, 0, stream>>>(xw, dvv, yb, n * 32, 32);
        dim3 g((n + 63) / 64, S);
        k_agg<unsigned char, 32><<<g, 256, 0, stream>>>(A, yb, part, n, n, chunk);
        k_aggfin<32><<<(n * 32 + 255) / 256, 256, 0, stream>>>(part, S, yb, dvv, bias, outv, n, relu);
    };
    auto gcn_u8_16 = [&](const unsigned char* A, int n, const float* xin, int K, const float* W,
                         const float* bias, const float* dvv, int relu, float* outv, int S, int chunk) {
        k_xw2<16><<<(n + 15) / 16, 256, 0, stream>>>(xin, W, xw, n, K);
        k_scaley<<<(n * 16 + 255) / 256, 256, 0, stream>>>(xw, dvv, yb, n * 16, 16);
        dim3 g((n + 63) / 64, S);
        k_agg<unsigned char, 16><<<g, 256, 0, stream>>>(A, yb, part, n, n, chunk);
        k_aggfin<16><<<(n * 16 + 255) / 256, 256, 0, stream>>>(part, S, yb, dvv, bias, outv, n, relu);
    };
    auto gcn_f = [&](const float* A, int n, const float* xin, int K, const float* W,
                     const float* bias, const float* dvv, int relu, float* outv, int S, int chunk) {
        k_xw2<32><<<(n + 7) / 8, 256, 0, stream>>>(xin, W, xw, n, K);
        k_scaley<<<(n * 32 + 255) / 256, 256, 0, stream>>>(xw, dvv, yb, n * 32, 32);
        dim3 g((n + 63) / 64, S);
        k_agg<float, 32><<<g, 256, 0, stream>>>(A, yb, part, n, n, chunk);
        k_aggfin<32><<<(n * 32 + 255) / 256, 256, 0, stream>>>(part, S, yb, dvv, bias, outv, n, relu);
    };
    auto pool = [&](const float* xin, const float* p, int n, int k, int* perm, float* xpo) {
        k_score<<<(n + 255) / 256, 256, 0, stream>>>(xin, p, sc, n);
        k_fill0_u32<<<16, 256, 0, stream>>>((unsigned*)rk, (size_t)n);
        dim3 gr((n + 255) / 256, (n + RCH - 1) / RCH);
        k_rank2<<<gr, 256, 0, stream>>>(sc, rk, n);
        k_perm<<<(n + 255) / 256, 256, 0, stream>>>(rk, perm, n, k);
        k_poolx<<<(k * HID + 255) / 256, 256, 0, stream>>>(xin, sc, perm, xpo, k);
    };

    // build dense adjacency + transpose
    k_fill0_u32<<<2048, 256, 0, stream>>>((unsigned*)A0u, (size_t)N0 * N0 / 4);
    k_fill0_u32<<<2048, 256, 0, stream>>>((unsigned*)A0T, (size_t)N0 * N0 / 4);
    k_scatter2<<<(NE + 255) / 256, 256, 0, stream>>>(ei, (unsigned*)A0u, (unsigned*)A0T);

    // degrees (once per level)
    k_deg8<<<N0, 256, 0, stream>>>(A0u, N0, dv0);

    // ---- down path ----
    gcn_u8_32(A0u, N0, x, FIN, W0, b0, dv0, 1, x0, 4, 1024);
    pool(x0, p0, N0, KP1, pm0, xp);

    k_prep8<<<2048, 256, 0, stream>>>(A0u, N0, 4096, pm0, KP1, Abf);
    k_prep8<<<2048, 256, 0, stream>>>(A0T, N0, 4096, pm0, KP1, Bbf);
    k_mfma_pool<<<dim3(16, 16), 256, 0, stream>>>(Abf, Bbf, A1, 4096, KP1);

    k_degf<<<KP1, 256, 0, stream>>>(A1, KP1, dv1);
    gcn_f(A1, KP1, xp, HID, W1, b1, dv1, 1, x1, 8, 256);
    k_tr_f32<<<dim3(63, 63), 256, 0, stream>>>(A1, A1T, KP1);
    pool(x1, p1, KP1, KP2, pm1, xp);

    k_prepf<<<1024, 256, 0, stream>>>(A1, KP1, 2048, pm1, KP2, Abf);
    k_prepf<<<1024, 256, 0, stream>>>(A1T, KP1, 2048, pm1, KP2, Bbf);
    k_mfma_pool<<<dim3(8, 8), 256, 0, stream>>>(Abf, Bbf, A2, 2048, KP2);

    k_degf<<<KP2, 256, 0, stream>>>(A2, KP2, dv2);
    gcn_f(A2, KP2, xp, HID, W2, b2, dv2, 1, x2, 16, 64);
    pool(x2, p2, KP2, KP3, pm2, xp);

    // L2 augment+pool: exact fp32, split-K (S=16) for occupancy; partials reuse Abf (idle here)
    {
        size_t tot = (size_t)KP2 * KP3;
        k_gcols<float><<<(int)((tot + 255) / 256), 256, 0, stream>>>(A2, pm2, CG, KP2, KP3);
        float* pbuf = (float*)Abf;   // 16 MB needed (16*500*500*4B), Abf has 16.8 MB
        k_gemm_pool_sk<<<dim3(8, 8, 16), 256, 0, stream>>>(A2, pm2, CG, pbuf, KP2, KP3, 64);
        k_gpfin<<<(KP3 * KP3 + 255) / 256, 256, 0, stream>>>(pbuf, 16, A3, KP3);
    }
    k_degf<<<KP3, 256, 0, stream>>>(A3, KP3, dv3);
    gcn_f(A3, KP3, xp, HID, W3, b3, dv3, 1, x3, 8, 64);

    // ---- up path ----
    k_copy<<<(KP2 * HID + 255) / 256, 256, 0, stream>>>(hb, x2, KP2 * HID);
    k_scadd<<<(KP3 * HID + 255) / 256, 256, 0, stream>>>(hb, x3, pm2, KP3);
    gcn_f(A2, KP2, hb, HID, U0, c0, dv2, 1, ua, 16, 64);

    k_copy<<<(KP1 * HID + 255) / 256, 256, 0, stream>>>(hb, x1, KP1 * HID);
    k_scadd<<<(KP2 * HID + 255) / 256, 256, 0, stream>>>(hb, ua, pm1, KP2);
    gcn_f(A1, KP1, hb, HID, U1, c1, dv1, 1, ub, 8, 256);

    k_copy<<<(N0 * HID + 255) / 256, 256, 0, stream>>>(hb, x0, N0 * HID);
    k_scadd<<<(KP1 * HID + 255) / 256, 256, 0, stream>>>(hb, ub, pm0, KP1);
    gcn_u8_16(A0u, N0, hb, HID, U2, c2, dv0, 0, o16, 4, 1024);

    k_logsm<<<(N0 + 255) / 256, 256, 0, stream>>>(o16, out, N0);
}